// Round 17
// baseline (248.773 us; speedup 1.0000x reference)
//
#include <hip/hip_runtime.h>

#define NN 100000      // nodes
#define NE 1600000     // edges
#define NB 4096        // graphs
#define DIN 74
#define DPAD 80
#define DH1 100
#define DGD 20
#define DD2 200
#define DM1 128
#define DM2 32
#define NSEG 8
#define KPAD 4352      // 4221 padded to 8*544
#define KSEG 544
#define NBUK 256
#define BNODES 391     // nodes per bucket (256*391 >= 100000)
#define CAP 7000       // per-bucket capacity (mean 6256, +9 sigma)
#define EPB 3125       // edges per bucket block (NE/512)
#define PRE_BUK 512
#define PRE_PREP (KPAD/32 + 2)          // 138
#define PRE_CVT ((NN*DPAD+255)/256)     // 31250
typedef unsigned int uint;
typedef unsigned short ushort;
typedef __attribute__((ext_vector_type(8))) short bf16x8;
typedef __attribute__((ext_vector_type(4))) float f32x4;

__device__ __forceinline__ float bf2f(ushort u){ return __uint_as_float(((uint)u)<<16); }
__device__ __forceinline__ ushort f2bf(float f){
  uint u = __float_as_uint(f);
  return (ushort)((u + 0x7fffu + ((u >> 16) & 1u)) >> 16);   // RNE
}
// floor(d/391) for d < 100096 (M=ceil(2^32/391)=10984572; err term < 1/391)
__device__ __forceinline__ uint bucket_of(int d){
  return (uint)(((unsigned long long)(uint)d * 10984572ull) >> 32);
}
__device__ __forceinline__ void acc2u(float2& a, uint v){
  a.x += __uint_as_float(v << 16);
  a.y += __uint_as_float(v & 0xffff0000u);
}
__device__ __forceinline__ void acc8(float4& a, float4& b, uint4 v){
  a.x += __uint_as_float(v.x << 16);
  a.y += __uint_as_float(v.x & 0xffff0000u);
  a.z += __uint_as_float(v.y << 16);
  a.w += __uint_as_float(v.y & 0xffff0000u);
  b.x += __uint_as_float(v.z << 16);
  b.y += __uint_as_float(v.z & 0xffff0000u);
  b.z += __uint_as_float(v.w << 16);
  b.w += __uint_as_float(v.w & 0xffff0000u);
}

// ---------------- front-end mega-kernel: bucket sort | weight prep | cvt ----
__global__ __launch_bounds__(256) void k_pre(
      const int* __restrict__ src, const int* __restrict__ dst,
      int* __restrict__ bukCur, uint2* __restrict__ pairs,
      const float* __restrict__ Wf1, ushort* __restrict__ Bthi,
      const float* __restrict__ W1g, ushort* __restrict__ W1tb,
      const float* __restrict__ W2g, ushort* __restrict__ W2tb,
      const float* __restrict__ feat, ushort* __restrict__ fb){
  __shared__ __align__(16) char SM[35360];
  int blk = blockIdx.x, tid = threadIdx.x;
  if(blk < PRE_BUK){
    // ---- CSR phase A: LDS bucket sort (256 buckets), coalesced flush ----
    uint2* stage = (uint2*)SM;               // 25000 B
    ushort* bidx = (ushort*)(SM + 25000);    // 6250 B
    int* cnt   = (int*)(SM + 31252);         // 1024 B
    int* scanv = (int*)(SM + 32276);         // 1024 B
    int* gadj  = (int*)(SM + 33300);         // 1024 B
    int* cur   = (int*)(SM + 34324);         // 1024 B
    cnt[tid] = 0;                            // NBUK == blockDim == 256
    __syncthreads();
    int e0 = blk * EPB;
    for(int i = tid; i < EPB; i += 256)
      atomicAdd(&cnt[bucket_of(dst[e0 + i])], 1);
    __syncthreads();
    int c = cnt[tid];
    scanv[tid] = c;
    __syncthreads();
    for(int off=1; off<NBUK; off<<=1){
      int v = (tid >= off) ? scanv[tid-off] : 0;
      __syncthreads();
      scanv[tid] += v;
      __syncthreads();
    }
    int excl = scanv[tid] - c;
    int base = atomicAdd(&bukCur[tid], c);
    gadj[tid] = tid*CAP + base - excl;
    cur[tid]  = excl;
    __syncthreads();
    for(int i = tid; i < EPB; i += 256){
      int d = dst[e0 + i];
      int s = src[e0 + i];
      uint b = bucket_of(d);
      int p = atomicAdd(&cur[b], 1);
      stage[p] = make_uint2((uint)s, (uint)d);
      bidx[p] = (ushort)b;
    }
    __syncthreads();
    for(int i = tid; i < EPB; i += 256)
      pairs[(size_t)gadj[bidx[i]] + i] = stage[i];
  } else if(blk < PRE_BUK + KPAD/32){
    // ---- fusion W1 -> bf16 transposed [128][KPAD] ----
    float (*Wl)[128] = (float(*)[128])SM;    // 16 KB
    int k0 = (blk - PRE_BUK) * 32;
    for(int idx=tid; idx<32*128; idx+=256){
      int kk = idx >> 7, n = idx & 127;
      int k = k0 + kk;
      Wl[kk][n] = (k < 4221) ? Wf1[(size_t)k*128 + n] : 0.f;
    }
    __syncthreads();
    int n = tid >> 1, kh = (tid & 1) * 16;
    uint ph[8];
    #pragma unroll
    for(int e=0;e<8;e++){
      ushort h0 = f2bf(Wl[kh+2*e][n]);
      ushort h1 = f2bf(Wl[kh+2*e+1][n]);
      ph[e] = (uint)h0 | ((uint)h1 << 16);
    }
    uint4* dh = (uint4*)(Bthi + (size_t)n*KPAD + k0 + kh);
    dh[0] = make_uint4(ph[0],ph[1],ph[2],ph[3]);
    dh[1] = make_uint4(ph[4],ph[5],ph[6],ph[7]);
  } else if(blk == PRE_BUK + KPAD/32){
    for(int idx = tid; idx < 112*96; idx += 256){
      int n = idx / 96, k = idx - n*96;
      float v = (n < DH1 && k < DIN) ? W1g[(size_t)k*DH1 + n] : 0.f;
      W1tb[idx] = f2bf(v);
    }
  } else if(blk == PRE_BUK + KPAD/32 + 1){
    for(int idx = tid; idx < 32*128; idx += 256){
      int n = idx >> 7, k = idx & 127;
      float v = (n < DGD && k < DH1) ? W2g[(size_t)k*DGD + n] : 0.f;
      W2tb[idx] = f2bf(v);
    }
  } else {
    // ---- feat -> bf16 padded [N][80] ----
    int idx = (blk - (PRE_BUK + PRE_PREP))*256 + tid;
    if(idx < NN*DPAD){
      int row = idx / DPAD, d = idx - row*DPAD;
      fb[idx] = (d < DIN) ? f2bf(feat[(size_t)row*DIN + d]) : (ushort)0;
    }
  }
}

// ---------------- CSR phase B (256 blocks) + gofs-by-binary-search ----------
__global__ __launch_bounds__(512) void k_csr2(const uint2* __restrict__ pairs,
      const int* __restrict__ bukTot, int* __restrict__ rowptr, int* __restrict__ adj,
      const int* __restrict__ gid, int* __restrict__ gofs){
  if(blockIdx.x == NBUK){
    int tid = threadIdx.x;
    for(int g = tid; g <= NB; g += 512){
      int lo = 0, hi = NN;
      while(lo < hi){
        int mid = (lo + hi) >> 1;
        if(gid[mid] < g) lo = mid + 1; else hi = mid;
      }
      gofs[g] = lo;
    }
    return;
  }
  __shared__ int degL[BNODES];
  __shared__ int curL[BNODES];
  __shared__ int csum[NBUK];
  __shared__ int tsum[512];
  int b = blockIdx.x, tid = threadIdx.x;
  // exclusive prefix of bucket counts (LDS scan over 256 entries)
  if(tid < NBUK) csum[tid] = bukTot[tid];
  __syncthreads();
  for(int off=1; off<NBUK; off<<=1){
    int v = (tid < NBUK && tid >= off) ? csum[tid-off] : 0;
    __syncthreads();
    if(tid < NBUK) csum[tid] += v;
    __syncthreads();
  }
  int gbase = (b == 0) ? 0 : csum[b-1];
  int tot = bukTot[b];
  int d0 = b*BNODES;
  int nloc = min(BNODES, NN - d0);
  for(int i=tid;i<nloc;i+=512){ degL[i]=0; curL[i]=0; }
  __syncthreads();
  const uint2* pb = pairs + (size_t)b*CAP;
  for(int i=tid;i<tot;i+=512)
    atomicAdd(&degL[(int)pb[i].y - d0], 1);
  __syncthreads();
  // exclusive scan of degL[0..nloc) — one slot per thread (nloc <= 391 < 512)
  int s = (tid < nloc) ? degL[tid] : 0;
  tsum[tid] = s;
  __syncthreads();
  for(int off=1; off<512; off<<=1){
    int v = (tid >= off) ? tsum[tid-off] : 0;
    __syncthreads();
    tsum[tid] += v;
    __syncthreads();
  }
  int excl = tsum[tid] - s;
  if(tid < nloc){
    degL[tid] = excl;
    rowptr[d0 + tid] = gbase + excl;
  }
  if(b == NBUK-1 && tid == 0) rowptr[NN] = gbase + tot;
  __syncthreads();
  for(int i=tid;i<tot;i+=512){
    uint2 pr = pb[i];
    int dl = (int)pr.y - d0;
    int pos = atomicAdd(&curL[dl],1);
    adj[gbase + degL[dl] + pos] = (int)pr.x;
  }
}

// ---------------- GCN layer 1 mean-agg: uint4 gathers, 6 edges x 10 lanes ---
__global__ void k_agg1e(const ushort* __restrict__ fb, const float* __restrict__ feat,
                        const int* __restrict__ rowptr, const int* __restrict__ adj,
                        ushort* __restrict__ outb){
  int wid  = (blockIdx.x*blockDim.x + threadIdx.x) >> 6;
  int lane = threadIdx.x & 63;
  if(wid >= NN) return;
  int r0 = rowptr[wid], r1 = rowptr[wid+1];
  int eo = lane / 10;
  int part = lane - eo*10;
  bool act = lane < 60;
  if(!act){ eo = 0; part = 0; }
  float4 la0={0,0,0,0}, ha0={0,0,0,0}, la1={0,0,0,0}, ha1={0,0,0,0};
  float4 la2={0,0,0,0}, ha2={0,0,0,0}, la3={0,0,0,0}, ha3={0,0,0,0};
  for(int j = r0; j < r1; j += 24){
    int j0 = j + eo, j1 = j + 6 + eo, j2 = j + 12 + eo, j3 = j + 18 + eo;
    bool p0 = act && (j0 < r1), p1 = act && (j1 < r1);
    bool p2 = act && (j2 < r1), p3 = act && (j3 < r1);
    int s0 = adj[p0 ? j0 : r0];
    int s1 = adj[p1 ? j1 : r0];
    int s2 = adj[p2 ? j2 : r0];
    int s3 = adj[p3 ? j3 : r0];
    uint4 v0 = *(const uint4*)&fb[(size_t)s0*DPAD + part*8];
    uint4 v1 = *(const uint4*)&fb[(size_t)s1*DPAD + part*8];
    uint4 v2 = *(const uint4*)&fb[(size_t)s2*DPAD + part*8];
    uint4 v3 = *(const uint4*)&fb[(size_t)s3*DPAD + part*8];
    if(p0) acc8(la0, ha0, v0);
    if(p1) acc8(la1, ha1, v1);
    if(p2) acc8(la2, ha2, v2);
    if(p3) acc8(la3, ha3, v3);
  }
  float4 lo, hi;
  lo.x = (la0.x+la1.x)+(la2.x+la3.x); lo.y = (la0.y+la1.y)+(la2.y+la3.y);
  lo.z = (la0.z+la1.z)+(la2.z+la3.z); lo.w = (la0.w+la1.w)+(la2.w+la3.w);
  hi.x = (ha0.x+ha1.x)+(ha2.x+ha3.x); hi.y = (ha0.y+ha1.y)+(ha2.y+ha3.y);
  hi.z = (ha0.z+ha1.z)+(ha2.z+ha3.z); hi.w = (ha0.w+ha1.w)+(ha2.w+ha3.w);
  float4 L1,H1,L2,H2,L3,H3,L4,H4,L5,H5;
  #define SH4(dst,src,off) dst.x=__shfl(src.x,lane+off,64); dst.y=__shfl(src.y,lane+off,64); \
                           dst.z=__shfl(src.z,lane+off,64); dst.w=__shfl(src.w,lane+off,64);
  SH4(L1,lo,10) SH4(H1,hi,10)
  SH4(L2,lo,20) SH4(H2,hi,20)
  SH4(L3,lo,30) SH4(H3,hi,30)
  SH4(L4,lo,40) SH4(H4,hi,40)
  SH4(L5,lo,50) SH4(H5,hi,50)
  #undef SH4
  if(lane < 10){
    float4 tl, th;
    tl.x = ((lo.x+L1.x)+(L2.x+L3.x))+(L4.x+L5.x);
    tl.y = ((lo.y+L1.y)+(L2.y+L3.y))+(L4.y+L5.y);
    tl.z = ((lo.z+L1.z)+(L2.z+L3.z))+(L4.z+L5.z);
    tl.w = ((lo.w+L1.w)+(L2.w+L3.w))+(L4.w+L5.w);
    th.x = ((hi.x+H1.x)+(H2.x+H3.x))+(H4.x+H5.x);
    th.y = ((hi.y+H1.y)+(H2.y+H3.y))+(H4.y+H5.y);
    th.z = ((hi.z+H1.z)+(H2.z+H3.z))+(H4.z+H5.z);
    th.w = ((hi.w+H1.w)+(H2.w+H3.w))+(H4.w+H5.w);
    int d = r1 - r0;
    int dbase = part*8;
    if(d > 0){
      float inv = 1.f/(float)d;
      tl.x*=inv; tl.y*=inv; tl.z*=inv; tl.w*=inv;
      th.x*=inv; th.y*=inv; th.z*=inv; th.w*=inv;
    } else {
      const float* fr = feat + (size_t)wid*DIN;   // exact fallback
      tl.x = (dbase+0 < DIN) ? fr[dbase+0] : 0.f;
      tl.y = (dbase+1 < DIN) ? fr[dbase+1] : 0.f;
      tl.z = (dbase+2 < DIN) ? fr[dbase+2] : 0.f;
      tl.w = (dbase+3 < DIN) ? fr[dbase+3] : 0.f;
      th.x = (dbase+4 < DIN) ? fr[dbase+4] : 0.f;
      th.y = (dbase+5 < DIN) ? fr[dbase+5] : 0.f;
      th.z = (dbase+6 < DIN) ? fr[dbase+6] : 0.f;
      th.w = (dbase+7 < DIN) ? fr[dbase+7] : 0.f;
    }
    uint4 o;
    o.x = (uint)f2bf(tl.x) | ((uint)f2bf(tl.y) << 16);
    o.y = (uint)f2bf(tl.z) | ((uint)f2bf(tl.w) << 16);
    o.z = (uint)f2bf(th.x) | ((uint)f2bf(th.y) << 16);
    o.w = (uint)f2bf(th.z) | ((uint)f2bf(th.w) << 16);
    *(uint4*)&outb[(size_t)wid*DPAD + dbase] = o;
  }
}

// ---------------- fused GCN linear layers: y2 = relu(agg@W1+b1)@W2 ----------
__global__ __launch_bounds__(256) void k_gcn12(const ushort* __restrict__ Ab80,
      const ushort* __restrict__ W1tb, const ushort* __restrict__ W2tb,
      const float* __restrict__ b1, ushort* __restrict__ y2b){
  __shared__ ushort L[24960];      // 49920 B union
  ushort* As  = L;                 // [128][104] phase1
  ushort* Ws  = L + 128*104;       // [112][104] phase1
  ushort* Hs  = L;                 // [128][136] phase2
  ushort* W2s = L + 128*136;       // [32][136]  phase2
  int tid = threadIdx.x;
  int n0 = blockIdx.x*128;
  #pragma unroll
  for(int p=0;p<5;p++){
    int idx = tid + p*256;
    int row = idx/10, c = (idx - row*10)*8;
    uint4 v = {0,0,0,0};
    if(n0+row < NN) v = *(const uint4*)&Ab80[(size_t)(n0+row)*DPAD + c];
    *(uint4*)&As[row*104 + c] = v;
  }
  { int row = tid>>1, c = 80 + (tid&1)*8;
    *(uint4*)&As[row*104 + c] = (uint4){0,0,0,0}; }
  #pragma unroll
  for(int p=0;p<6;p++){
    int idx = tid + p*256;
    if(idx < 1344){
      int row = idx/12, c = (idx - row*12)*8;
      *(uint4*)&Ws[row*104 + c] = *(const uint4*)&W1tb[row*96 + c];
    }
  }
  __syncthreads();
  int lane = tid & 63, w = tid >> 6;
  int wm = w*32;
  int frow = lane & 15, fk = (lane>>4)*8;
  f32x4 acc[2][7];
  #pragma unroll
  for(int a=0;a<2;a++)
    #pragma unroll
    for(int b=0;b<7;b++) acc[a][b] = (f32x4){0.f,0.f,0.f,0.f};
  #pragma unroll
  for(int ks=0; ks<3; ks++){
    bf16x8 af[2], bfr[7];
    #pragma unroll
    for(int mt=0;mt<2;mt++) af[mt] = *(const bf16x8*)&As[(wm+mt*16+frow)*104 + ks*32 + fk];
    #pragma unroll
    for(int nt=0;nt<7;nt++) bfr[nt] = *(const bf16x8*)&Ws[(nt*16+frow)*104 + ks*32 + fk];
    #pragma unroll
    for(int mt=0;mt<2;mt++)
      #pragma unroll
      for(int nt=0;nt<7;nt++)
        acc[mt][nt] = __builtin_amdgcn_mfma_f32_16x16x32_bf16(af[mt], bfr[nt], acc[mt][nt], 0, 0, 0);
  }
  int crow = (lane>>4)*4, ccol = lane & 15;
  float bv[7];
  #pragma unroll
  for(int nt=0;nt<7;nt++){
    int c = nt*16 + ccol;
    bv[nt] = (c < DH1) ? b1[c] : 0.f;
  }
  __syncthreads();
  #pragma unroll
  for(int mt=0;mt<2;mt++)
    #pragma unroll
    for(int nt=0;nt<7;nt++)
      #pragma unroll
      for(int rr=0;rr<4;rr++)
        Hs[(wm + mt*16 + crow + rr)*136 + nt*16 + ccol] =
            f2bf(fmaxf(acc[mt][nt][rr] + bv[nt], 0.f));
  { int row = tid>>1, c = 112 + (tid&1)*8;
    *(uint4*)&Hs[row*136 + c] = (uint4){0,0,0,0}; }
  #pragma unroll
  for(int p=0;p<2;p++){
    int idx = tid + p*256;
    int row = idx >> 4, c = (idx & 15)*8;
    *(uint4*)&W2s[row*136 + c] = *(const uint4*)&W2tb[row*128 + c];
  }
  __syncthreads();
  f32x4 acc2[2][2];
  #pragma unroll
  for(int a=0;a<2;a++){ acc2[a][0]=(f32x4){0,0,0,0}; acc2[a][1]=(f32x4){0,0,0,0}; }
  #pragma unroll
  for(int ks=0; ks<4; ks++){
    bf16x8 af2[2], bf2r[2];
    #pragma unroll
    for(int mt=0;mt<2;mt++) af2[mt] = *(const bf16x8*)&Hs[(wm+mt*16+frow)*136 + ks*32 + fk];
    #pragma unroll
    for(int nt=0;nt<2;nt++) bf2r[nt] = *(const bf16x8*)&W2s[(nt*16+frow)*136 + ks*32 + fk];
    #pragma unroll
    for(int mt=0;mt<2;mt++)
      #pragma unroll
      for(int nt=0;nt<2;nt++)
        acc2[mt][nt] = __builtin_amdgcn_mfma_f32_16x16x32_bf16(af2[mt], bf2r[nt], acc2[mt][nt], 0, 0, 0);
  }
  #pragma unroll
  for(int mt=0;mt<2;mt++)
    #pragma unroll
    for(int nt=0;nt<2;nt++)
      #pragma unroll
      for(int rr=0;rr<4;rr++){
        int col = nt*16 + ccol;
        int r = n0 + wm + mt*16 + crow + rr;
        if(col < DGD && r < NN)
          y2b[(size_t)r*DGD + col] = f2bf(acc2[mt][nt][rr]);
      }
}

// agg2: uint2 gathers (4 dims), 12 edges x 5 lanes, 48-edge window, no atomics
__global__ void k_agg2d(const ushort* __restrict__ y2b, const int* __restrict__ rowptr,
                        const int* __restrict__ adj, const float* __restrict__ b2,
                        float* __restrict__ y3){
  int wid  = (blockIdx.x*blockDim.x + threadIdx.x) >> 6;
  int lane = threadIdx.x & 63;
  if(wid >= NN) return;
  int r0 = rowptr[wid], r1 = rowptr[wid+1];
  int eo = lane / 5;
  int part = lane - eo*5;
  bool act = lane < 60;
  if(!act){ eo = 0; part = 0; }
  float4 a0={0,0,0,0}, a1={0,0,0,0}, a2={0,0,0,0}, a3={0,0,0,0};
  for(int j = r0; j < r1; j += 48){
    int j0 = j + eo, j1 = j + 12 + eo, j2 = j + 24 + eo, j3 = j + 36 + eo;
    bool p0 = act && (j0 < r1), p1 = act && (j1 < r1);
    bool p2 = act && (j2 < r1), p3 = act && (j3 < r1);
    int s0 = adj[p0 ? j0 : r0];
    int s1 = adj[p1 ? j1 : r0];
    int s2 = adj[p2 ? j2 : r0];
    int s3 = adj[p3 ? j3 : r0];
    uint2 v0 = *(const uint2*)&y2b[(size_t)s0*DGD + part*4];
    uint2 v1 = *(const uint2*)&y2b[(size_t)s1*DGD + part*4];
    uint2 v2 = *(const uint2*)&y2b[(size_t)s2*DGD + part*4];
    uint2 v3 = *(const uint2*)&y2b[(size_t)s3*DGD + part*4];
    if(p0){ acc2u(*(float2*)&a0.x, v0.x); acc2u(*(float2*)&a0.z, v0.y); }
    if(p1){ acc2u(*(float2*)&a1.x, v1.x); acc2u(*(float2*)&a1.z, v1.y); }
    if(p2){ acc2u(*(float2*)&a2.x, v2.x); acc2u(*(float2*)&a2.z, v2.y); }
    if(p3){ acc2u(*(float2*)&a3.x, v3.x); acc2u(*(float2*)&a3.z, v3.y); }
  }
  float4 t;
  t.x = (a0.x+a1.x)+(a2.x+a3.x);
  t.y = (a0.y+a1.y)+(a2.y+a3.y);
  t.z = (a0.z+a1.z)+(a2.z+a3.z);
  t.w = (a0.w+a1.w)+(a2.w+a3.w);
  t.x += __shfl(t.x, lane+30, 64); t.y += __shfl(t.y, lane+30, 64);
  t.z += __shfl(t.z, lane+30, 64); t.w += __shfl(t.w, lane+30, 64);
  t.x += __shfl(t.x, lane+15, 64); t.y += __shfl(t.y, lane+15, 64);
  t.z += __shfl(t.z, lane+15, 64); t.w += __shfl(t.w, lane+15, 64);
  float ux = __shfl(t.x, lane+5, 64),  uy = __shfl(t.y, lane+5, 64);
  float uz = __shfl(t.z, lane+5, 64),  uw = __shfl(t.w, lane+5, 64);
  float wx = __shfl(t.x, lane+10, 64), wy = __shfl(t.y, lane+10, 64);
  float wz = __shfl(t.z, lane+10, 64), ww = __shfl(t.w, lane+10, 64);
  if(lane < 5){
    float tx = t.x + ux + wx, ty = t.y + uy + wy;
    float tz = t.z + uz + wz, tw = t.w + uw + ww;
    int d = r1 - r0;
    float bx, by, bz, bw;
    if(d > 0){
      float inv = 1.f/(float)d;
      bx = tx*inv; by = ty*inv; bz = tz*inv; bw = tw*inv;
    } else {
      uint2 v = *(const uint2*)&y2b[(size_t)wid*DGD + lane*4];
      bx = __uint_as_float(v.x << 16);
      by = __uint_as_float(v.x & 0xffff0000u);
      bz = __uint_as_float(v.y << 16);
      bw = __uint_as_float(v.y & 0xffff0000u);
    }
    float4 o;
    o.x = fmaxf(bx + b2[lane*4+0], 0.f);
    o.y = fmaxf(by + b2[lane*4+1], 0.f);
    o.z = fmaxf(bz + b2[lane*4+2], 0.f);
    o.w = fmaxf(bw + b2[lane*4+3], 0.f);
    *(float4*)&y3[(size_t)wid*DGD + lane*4] = o;
  }
}

// head3: per-graph mean + attention softmax + DIRECT A' row write (bf16)
__global__ __launch_bounds__(256) void k_head3(const float* __restrict__ y3,
      const int* __restrict__ gofs, const float* __restrict__ Wat,
      const float* __restrict__ desc2d, ushort* __restrict__ Ab){
  int g = blockIdx.x, t = threadIdx.x;
  int n0 = gofs[g], n1 = gofs[g+1];
  int cnt = n1 - n0;
  __shared__ float part[240];
  __shared__ float hgaL[21];
  __shared__ float daaL[201];
  __shared__ float red[256];
  if(t < 240){
    int grp = t/20, dim = t - grp*20;
    float a = 0.f;
    for(int n = n0 + grp; n < n1; n += 12) a += y3[(size_t)n*DGD + dim];
    part[t] = a;
  }
  __syncthreads();
  if(t < DGD){
    float s = 0.f;
    #pragma unroll
    for(int k=0;k<12;k++) s += part[k*20 + t];
    hgaL[t] = s / (float)max(cnt, 1);
  }
  if(t == DGD) hgaL[20] = 1.f;
  __syncthreads();
  float logit = 0.f;
  if(t < DD2){
    #pragma unroll
    for(int k=0;k<DGD;k++) logit += hgaL[k]*Wat[k*DD2 + t];
  }
  float v = (t < DD2) ? logit : -1e30f;
  red[t] = v; __syncthreads();
  for(int off=128; off>=1; off>>=1){ if(t<off) red[t]=fmaxf(red[t],red[t+off]); __syncthreads(); }
  float mx = red[0]; __syncthreads();
  float e = (t < DD2) ? expf(logit - mx) : 0.f;
  red[t] = e; __syncthreads();
  for(int off=128; off>=1; off>>=1){ if(t<off) red[t]+=red[t+off]; __syncthreads(); }
  float s = red[0];
  if(t < DD2) daaL[t] = (e/s)*desc2d[(size_t)g*DD2 + t];
  if(t == DD2) daaL[200] = 1.f;
  __syncthreads();
  ushort* arow = Ab + (size_t)g*KPAD;
  #pragma unroll
  for(int p=0;p<17;p++){
    int k = t + 256*p;
    ushort o = 0;
    if(k < 4221){
      int i = (int)(((uint)k * 83470u) >> 24);   // floor(k/201), exact for k<4221
      int j = k - i*201;
      o = f2bf(hgaL[i]*daaL[j]);
    }
    arow[k] = o;
  }
}

// ---------------- fusion GEMM v6: single-B bf16, M-tile 64, grid (64,8) -----
__global__ __launch_bounds__(256) void k_fuse6(const ushort* __restrict__ Ab,
                                               const ushort* __restrict__ Bthi,
                                               float* __restrict__ zp){
  __shared__ ushort Al[64][40];
  __shared__ ushort Bl[128][40];
  int tid = threadIdx.x;
  int m0 = blockIdx.x * 64;
  int seg = blockIdx.y;
  int lane = tid & 63;
  int w = tid >> 6;
  int wm = (w >> 1) * 32;
  int wn = (w & 1) * 64;
  f32x4 acc[2][4];
  #pragma unroll
  for(int a=0;a<2;a++)
    #pragma unroll
    for(int b=0;b<4;b++) acc[a][b] = (f32x4){0.f,0.f,0.f,0.f};

  int ar = tid >> 2;
  int as = (tid & 3) * 8;
  int br = tid >> 1;
  int bs = (tid & 1) * 16;
  const uint4* gA = (const uint4*)(Ab   + (size_t)(m0 + ar)*KPAD + seg*KSEG + as);
  const uint4* gB = (const uint4*)(Bthi + (size_t)br*KPAD + seg*KSEG + bs);

  int frow = lane & 15;
  int fk   = (lane >> 4) * 8;

  for(int ks=0; ks<17; ks++){
    uint4 va = gA[0];
    uint4 vb0 = gB[0], vb1 = gB[1];
    gA += 4; gB += 4;                // one k-step = 32 shorts = 4 uint4
    __syncthreads();
    *(uint4*)&Al[ar][as]   = va;
    *(uint4*)&Bl[br][bs]   = vb0;
    *(uint4*)&Bl[br][bs+8] = vb1;
    __syncthreads();
    bf16x8 af[2], bh[4];
    #pragma unroll
    for(int mt=0;mt<2;mt++) af[mt] = *(const bf16x8*)&Al[wm + mt*16 + frow][fk];
    #pragma unroll
    for(int nt=0;nt<4;nt++) bh[nt] = *(const bf16x8*)&Bl[wn + nt*16 + frow][fk];
    #pragma unroll
    for(int mt=0;mt<2;mt++)
      #pragma unroll
      for(int nt=0;nt<4;nt++)
        acc[mt][nt] = __builtin_amdgcn_mfma_f32_16x16x32_bf16(af[mt], bh[nt], acc[mt][nt], 0, 0, 0);
  }
  float* zb = zp + ((size_t)seg*NB + m0)*128;
  int drow = (lane >> 4) * 4;
  int dcol = lane & 15;
  #pragma unroll
  for(int mt=0;mt<2;mt++)
    #pragma unroll
    for(int nt=0;nt<4;nt++)
      #pragma unroll
      for(int rr=0;rr<4;rr++)
        zb[(size_t)(wm + mt*16 + drow + rr)*128 + wn + nt*16 + dcol] = acc[mt][nt][rr];
}

__global__ void k_reduce(const float* __restrict__ zp, const float* __restrict__ b1,
                         float* __restrict__ z1){
  int idx = blockIdx.x*256 + threadIdx.x;
  if(idx >= NB*32) return;
  const float4* z = (const float4*)zp;
  float4 o = ((const float4*)b1)[idx & 31];
  #pragma unroll
  for(int s=0;s<NSEG;s++){
    float4 a = z[idx + (size_t)s*NB*32];
    o.x += a.x; o.y += a.y; o.z += a.z; o.w += a.w;
  }
  ((float4*)z1)[idx] = o;
}

// BN stats -> folded scale/shift
__global__ void k_bnstats(const float* __restrict__ X, int C,
                          const float* __restrict__ gamma, const float* __restrict__ beta,
                          float* __restrict__ scale, float* __restrict__ shift){
  int c = blockIdx.x;
  float s=0.f, s2=0.f;
  for(int r=threadIdx.x; r<NB; r+=256){
    float v = X[(size_t)r*C + c];
    s += v; s2 += v*v;
  }
  __shared__ float sh[256], sh2[256];
  sh[threadIdx.x]=s; sh2[threadIdx.x]=s2;
  __syncthreads();
  for(int off=128; off>=1; off>>=1){
    if(threadIdx.x<off){ sh[threadIdx.x]+=sh[threadIdx.x+off]; sh2[threadIdx.x]+=sh2[threadIdx.x+off]; }
    __syncthreads();
  }
  if(threadIdx.x==0){
    float mu  = sh[0]*(1.0f/NB);
    float var = sh2[0]*(1.0f/NB) - mu*mu;
    float a = gamma[c]*rsqrtf(var + 1e-5f);
    scale[c] = a;
    shift[c] = beta[c] - mu*a;
  }
}

__global__ void k_mlp2(const float* __restrict__ z1, const float* __restrict__ sc,
                       const float* __restrict__ sf, const float* __restrict__ W,
                       const float* __restrict__ bias, float* __restrict__ out){
  __shared__ float Wl[DM1*DM2];
  __shared__ float scl[DM1], sfl[DM1];
  for(int idx=threadIdx.x; idx<DM1*DM2; idx+=256) Wl[idx] = W[idx];
  if(threadIdx.x < DM1){ scl[threadIdx.x]=sc[threadIdx.x]; sfl[threadIdx.x]=sf[threadIdx.x]; }
  __syncthreads();
  int idx = blockIdx.x*256 + threadIdx.x;
  int r = idx >> 5, o = idx & 31;
  if(r >= NB) return;
  float acc = bias[o];
  const float* xr = z1 + (size_t)r*DM1;
  for(int k=0;k<DM1;k++){
    float xn = fmaxf(xr[k]*scl[k] + sfl[k], 0.f);
    acc += xn * Wl[k*DM2 + o];
  }
  out[(size_t)r*DM2 + o] = acc;
}

__global__ void k_final(const float* __restrict__ z2, const float* __restrict__ sc2,
                        const float* __restrict__ sf2, const float* __restrict__ W3,
                        const float* __restrict__ b3, float* __restrict__ out){
  int r = blockIdx.x*256 + threadIdx.x;
  if(r >= NB) return;
  float acc = b3[0];
  const float* xr = z2 + (size_t)r*DM2;
  #pragma unroll
  for(int o=0;o<DM2;o++){
    float xn = fmaxf(xr[o]*sc2[o] + sf2[o], 0.f);
    acc += xn * W3[o];
  }
  out[r] = acc;
}

extern "C" void kernel_launch(void* const* d_in, const int* in_sizes, int n_in,
                              void* d_out, int out_size, void* d_ws, size_t ws_size,
                              hipStream_t stream){
  (void)in_sizes; (void)n_in; (void)out_size; (void)ws_size;
  const float* feat   = (const float*)d_in[0];
  const float* desc2d = (const float*)d_in[1];
  const int*   esrc   = (const int*)d_in[3];
  const int*   edst   = (const int*)d_in[4];
  const int*   gid    = (const int*)d_in[5];
  const float* Wg1    = (const float*)d_in[6];
  const float* bg1    = (const float*)d_in[7];
  const float* Wg2    = (const float*)d_in[8];
  const float* bg2    = (const float*)d_in[9];
  const float* Wat    = (const float*)d_in[10];
  const float* Wf1    = (const float*)d_in[11];
  const float* bf1    = (const float*)d_in[12];
  const float* Wf2    = (const float*)d_in[13];
  const float* bf2    = (const float*)d_in[14];
  const float* Wf3    = (const float*)d_in[15];
  const float* bf3    = (const float*)d_in[16];
  const float* gamma1 = (const float*)d_in[17];
  const float* beta1  = (const float*)d_in[18];
  const float* gamma2 = (const float*)d_in[19];
  const float* beta2  = (const float*)d_in[20];
  float* out = (float*)d_out;

  char* base = (char*)d_ws;
  size_t off = 0;
  auto alloc = [&](size_t bytes)->void*{
    void* r = base + off;
    off = (off + bytes + 255) & ~(size_t)255;
    return r;
  };
  int*    rowptr = (int*)   alloc((size_t)(NN+1)*4);
  int*    gofs   = (int*)   alloc((size_t)(NB+1)*4);
  int*    adj    = (int*)   alloc((size_t)NE*4);
  int*    bukCur = (int*)   alloc((size_t)NBUK*4);
  float*  sc1    = (float*) alloc((size_t)DM1*4);
  float*  sf1    = (float*) alloc((size_t)DM1*4);
  float*  sc2    = (float*) alloc((size_t)DM2*4);
  float*  sf2    = (float*) alloc((size_t)DM2*4);
  ushort* W1thi  = (ushort*)alloc((size_t)128*KPAD*2);
  ushort* W1tb   = (ushort*)alloc((size_t)112*96*2);
  ushort* W2tb   = (ushort*)alloc((size_t)32*128*2);
  float*  z1     = (float*) alloc((size_t)NB*DM1*4);
  float*  z2     = (float*) alloc((size_t)NB*DM2*4);
  // R1 (32 MB): pairs(14.3M) -> agg80b(16M) -> zp(16.8M); y3 at +17M (8M)
  char*   R1     = (char*)  alloc((size_t)NN*DPAD*4);
  // R2 (35.7 MB): featb(16M) + y2b(@16M, 4M) -> Ab(35.7M)
  char*   R2     = (char*)  alloc((size_t)NB*KPAD*2);
  uint2*  pairs  = (uint2*) R1;
  ushort* agg80b = (ushort*)R1;
  float*  zp     = (float*) R1;
  float*  y3     = (float*) (R1 + (size_t)17*1024*1024);
  ushort* featb  = (ushort*)R2;
  ushort* y2b    = (ushort*)(R2 + (size_t)NN*DPAD*2);
  ushort* Ab     = (ushort*)R2;

  hipMemsetAsync(bukCur, 0, (size_t)NBUK*4, stream);

  k_pre <<<PRE_BUK + PRE_PREP + PRE_CVT, 256, 0, stream>>>(
      esrc, edst, bukCur, pairs, Wf1, W1thi, Wg1, W1tb, Wg2, W2tb, feat, featb);
  k_csr2<<<NBUK + 1, 512, 0, stream>>>(pairs, bukCur, rowptr, adj, gid, gofs);

  k_agg1e <<<(NN+3)/4, 256, 0, stream>>>(featb, feat, rowptr, adj, agg80b);
  k_gcn12 <<<(NN+127)/128, 256, 0, stream>>>(agg80b, W1tb, W2tb, bg1, y2b);
  k_agg2d <<<(NN+3)/4, 256, 0, stream>>>(y2b, rowptr, adj, bg2, y3);

  k_head3<<<NB, 256, 0, stream>>>(y3, gofs, Wat, desc2d, Ab);
  k_fuse6<<<dim3(64, NSEG), 256, 0, stream>>>(Ab, W1thi, zp);
  k_reduce<<<(NB*32+255)/256, 256, 0, stream>>>(zp, bf1, z1);

  k_bnstats<<<DM1, 256, 0, stream>>>(z1, DM1, gamma1, beta1, sc1, sf1);
  k_mlp2   <<<(NB*DM2)/256, 256, 0, stream>>>(z1, sc1, sf1, Wf2, bf2, z2);
  k_bnstats<<<DM2, 256, 0, stream>>>(z2, DM2, gamma2, beta2, sc2, sf2);
  k_final  <<<(NB+255)/256, 256, 0, stream>>>(z2, sc2, sf2, Wf3, bf3, out);
}

// Round 18
// 218.809 us; speedup vs baseline: 1.1369x; 1.1369x over previous
//
#include <hip/hip_runtime.h>

#define NN 100000      // nodes
#define NE 1600000     // edges
#define NB 4096        // graphs
#define DIN 74
#define DPAD 80
#define DH1 100
#define DGD 20
#define DD2 200
#define DM1 128
#define DM2 32
#define NSEG 8
#define KPAD 4352      // 4221 padded to 8*544
#define KSEG 544
#define NBUK 256
#define BNODES 391     // nodes per bucket (256*391 >= 100000)
#define CAP 7000       // per-bucket capacity (mean 6256, +9 sigma)
#define EPB 3125       // edges per bucket block (NE/512)
#define GOFS_BLKS 64
#define PRE_BUK 512
#define PRE_PREP (KPAD/32 + 2)          // 138
#define PRE_CVT ((NN*DPAD+255)/256)     // 31250
typedef unsigned int uint;
typedef unsigned short ushort;
typedef __attribute__((ext_vector_type(8))) short bf16x8;
typedef __attribute__((ext_vector_type(4))) float f32x4;

__device__ __forceinline__ float bf2f(ushort u){ return __uint_as_float(((uint)u)<<16); }
__device__ __forceinline__ ushort f2bf(float f){
  uint u = __float_as_uint(f);
  return (ushort)((u + 0x7fffu + ((u >> 16) & 1u)) >> 16);   // RNE
}
// floor(d/391) for d < 100096 (M=ceil(2^32/391)=10984572)
__device__ __forceinline__ uint bucket_of(int d){
  return (uint)(((unsigned long long)(uint)d * 10984572ull) >> 32);
}
__device__ __forceinline__ void acc2u(float2& a, uint v){
  a.x += __uint_as_float(v << 16);
  a.y += __uint_as_float(v & 0xffff0000u);
}
__device__ __forceinline__ void acc8(float4& a, float4& b, uint4 v){
  a.x += __uint_as_float(v.x << 16);
  a.y += __uint_as_float(v.x & 0xffff0000u);
  a.z += __uint_as_float(v.y << 16);
  a.w += __uint_as_float(v.y & 0xffff0000u);
  b.x += __uint_as_float(v.z << 16);
  b.y += __uint_as_float(v.z & 0xffff0000u);
  b.z += __uint_as_float(v.w << 16);
  b.w += __uint_as_float(v.w & 0xffff0000u);
}

// ---------------- front-end mega-kernel: bucket sort | weight prep | cvt ----
__global__ __launch_bounds__(256) void k_pre(
      const int* __restrict__ src, const int* __restrict__ dst,
      int* __restrict__ bukCur, uint2* __restrict__ pairs,
      const float* __restrict__ Wf1, ushort* __restrict__ Bthi,
      const float* __restrict__ W1g, ushort* __restrict__ W1tb,
      const float* __restrict__ W2g, ushort* __restrict__ W2tb,
      const float* __restrict__ feat, ushort* __restrict__ fb){
  __shared__ __align__(16) char SM[35360];
  int blk = blockIdx.x, tid = threadIdx.x;
  if(blk < PRE_BUK){
    // ---- CSR phase A: LDS bucket sort (256 buckets), coalesced flush ----
    uint2* stage = (uint2*)SM;               // 25000 B
    ushort* bidx = (ushort*)(SM + 25000);    // 6250 B
    int* cnt   = (int*)(SM + 31252);         // 1024 B
    int* scanv = (int*)(SM + 32276);         // 1024 B
    int* gadj  = (int*)(SM + 33300);         // 1024 B
    int* cur   = (int*)(SM + 34324);         // 1024 B
    cnt[tid] = 0;                            // NBUK == blockDim == 256
    __syncthreads();
    int e0 = blk * EPB;
    for(int i = tid; i < EPB; i += 256)
      atomicAdd(&cnt[bucket_of(dst[e0 + i])], 1);
    __syncthreads();
    int c = cnt[tid];
    scanv[tid] = c;
    __syncthreads();
    for(int off=1; off<NBUK; off<<=1){
      int v = (tid >= off) ? scanv[tid-off] : 0;
      __syncthreads();
      scanv[tid] += v;
      __syncthreads();
    }
    int excl = scanv[tid] - c;
    int base = atomicAdd(&bukCur[tid], c);
    gadj[tid] = tid*CAP + base - excl;
    cur[tid]  = excl;
    __syncthreads();
    for(int i = tid; i < EPB; i += 256){
      int d = dst[e0 + i];
      int s = src[e0 + i];
      uint b = bucket_of(d);
      int p = atomicAdd(&cur[b], 1);
      stage[p] = make_uint2((uint)s, (uint)d);
      bidx[p] = (ushort)b;
    }
    __syncthreads();
    for(int i = tid; i < EPB; i += 256)
      pairs[(size_t)gadj[bidx[i]] + i] = stage[i];
  } else if(blk < PRE_BUK + KPAD/32){
    // ---- fusion W1 -> bf16 transposed [128][KPAD] ----
    float (*Wl)[128] = (float(*)[128])SM;    // 16 KB
    int k0 = (blk - PRE_BUK) * 32;
    for(int idx=tid; idx<32*128; idx+=256){
      int kk = idx >> 7, n = idx & 127;
      int k = k0 + kk;
      Wl[kk][n] = (k < 4221) ? Wf1[(size_t)k*128 + n] : 0.f;
    }
    __syncthreads();
    int n = tid >> 1, kh = (tid & 1) * 16;
    uint ph[8];
    #pragma unroll
    for(int e=0;e<8;e++){
      ushort h0 = f2bf(Wl[kh+2*e][n]);
      ushort h1 = f2bf(Wl[kh+2*e+1][n]);
      ph[e] = (uint)h0 | ((uint)h1 << 16);
    }
    uint4* dh = (uint4*)(Bthi + (size_t)n*KPAD + k0 + kh);
    dh[0] = make_uint4(ph[0],ph[1],ph[2],ph[3]);
    dh[1] = make_uint4(ph[4],ph[5],ph[6],ph[7]);
  } else if(blk == PRE_BUK + KPAD/32){
    for(int idx = tid; idx < 112*96; idx += 256){
      int n = idx / 96, k = idx - n*96;
      float v = (n < DH1 && k < DIN) ? W1g[(size_t)k*DH1 + n] : 0.f;
      W1tb[idx] = f2bf(v);
    }
  } else if(blk == PRE_BUK + KPAD/32 + 1){
    for(int idx = tid; idx < 32*128; idx += 256){
      int n = idx >> 7, k = idx & 127;
      float v = (n < DGD && k < DH1) ? W2g[(size_t)k*DGD + n] : 0.f;
      W2tb[idx] = f2bf(v);
    }
  } else {
    // ---- feat -> bf16 padded [N][80] ----
    int idx = (blk - (PRE_BUK + PRE_PREP))*256 + tid;
    if(idx < NN*DPAD){
      int row = idx / DPAD, d = idx - row*DPAD;
      fb[idx] = (d < DIN) ? f2bf(feat[(size_t)row*DIN + d]) : (ushort)0;
    }
  }
}

// ---------------- CSR phase B (256 blocks) + parallel gofs scatter ----------
__global__ __launch_bounds__(512) void k_csr2(const uint2* __restrict__ pairs,
      const int* __restrict__ bukTot, int* __restrict__ rowptr, int* __restrict__ adj,
      const int* __restrict__ gid, int* __restrict__ gofs){
  if(blockIdx.x >= NBUK){
    // gofs[g] = lower_bound(gid, g): boundary scatter over sorted gid
    int t0 = (blockIdx.x - NBUK)*512 + threadIdx.x;
    for(int i = t0; i <= NN; i += GOFS_BLKS*512){
      int prev = (i == 0) ? -1 : gid[i-1];
      int cur  = (i < NN) ? gid[i] : NB;
      for(int g = prev+1; g <= cur; g++) gofs[g] = i;
    }
    return;
  }
  __shared__ int degL[BNODES];
  __shared__ int curL[BNODES];
  __shared__ int csum[NBUK];
  __shared__ int tsum[512];
  int b = blockIdx.x, tid = threadIdx.x;
  // exclusive prefix of bucket counts (LDS scan over 256 entries)
  if(tid < NBUK) csum[tid] = bukTot[tid];
  __syncthreads();
  for(int off=1; off<NBUK; off<<=1){
    int v = (tid < NBUK && tid >= off) ? csum[tid-off] : 0;
    __syncthreads();
    if(tid < NBUK) csum[tid] += v;
    __syncthreads();
  }
  int gbase = (b == 0) ? 0 : csum[b-1];
  int tot = bukTot[b];
  int d0 = b*BNODES;
  int nloc = min(BNODES, NN - d0);
  for(int i=tid;i<nloc;i+=512){ degL[i]=0; curL[i]=0; }
  __syncthreads();
  const uint2* pb = pairs + (size_t)b*CAP;
  for(int i=tid;i<tot;i+=512)
    atomicAdd(&degL[(int)pb[i].y - d0], 1);
  __syncthreads();
  // exclusive scan of degL[0..nloc) — one slot per thread (nloc <= 391 < 512)
  int s = (tid < nloc) ? degL[tid] : 0;
  tsum[tid] = s;
  __syncthreads();
  for(int off=1; off<512; off<<=1){
    int v = (tid >= off) ? tsum[tid-off] : 0;
    __syncthreads();
    tsum[tid] += v;
    __syncthreads();
  }
  int excl = tsum[tid] - s;
  if(tid < nloc){
    degL[tid] = excl;
    rowptr[d0 + tid] = gbase + excl;
  }
  if(b == NBUK-1 && tid == 0) rowptr[NN] = gbase + tot;
  __syncthreads();
  for(int i=tid;i<tot;i+=512){
    uint2 pr = pb[i];
    int dl = (int)pr.y - d0;
    int pos = atomicAdd(&curL[dl],1);
    adj[gbase + degL[dl] + pos] = (int)pr.x;
  }
}

// ---------------- GCN layer 1 mean-agg: uint4 gathers, 6 edges x 10 lanes ---
__global__ void k_agg1e(const ushort* __restrict__ fb, const float* __restrict__ feat,
                        const int* __restrict__ rowptr, const int* __restrict__ adj,
                        ushort* __restrict__ outb){
  int wid  = (blockIdx.x*blockDim.x + threadIdx.x) >> 6;
  int lane = threadIdx.x & 63;
  if(wid >= NN) return;
  int r0 = rowptr[wid], r1 = rowptr[wid+1];
  int eo = lane / 10;
  int part = lane - eo*10;
  bool act = lane < 60;
  if(!act){ eo = 0; part = 0; }
  float4 la0={0,0,0,0}, ha0={0,0,0,0}, la1={0,0,0,0}, ha1={0,0,0,0};
  float4 la2={0,0,0,0}, ha2={0,0,0,0}, la3={0,0,0,0}, ha3={0,0,0,0};
  for(int j = r0; j < r1; j += 24){
    int j0 = j + eo, j1 = j + 6 + eo, j2 = j + 12 + eo, j3 = j + 18 + eo;
    bool p0 = act && (j0 < r1), p1 = act && (j1 < r1);
    bool p2 = act && (j2 < r1), p3 = act && (j3 < r1);
    int s0 = adj[p0 ? j0 : r0];
    int s1 = adj[p1 ? j1 : r0];
    int s2 = adj[p2 ? j2 : r0];
    int s3 = adj[p3 ? j3 : r0];
    uint4 v0 = *(const uint4*)&fb[(size_t)s0*DPAD + part*8];
    uint4 v1 = *(const uint4*)&fb[(size_t)s1*DPAD + part*8];
    uint4 v2 = *(const uint4*)&fb[(size_t)s2*DPAD + part*8];
    uint4 v3 = *(const uint4*)&fb[(size_t)s3*DPAD + part*8];
    if(p0) acc8(la0, ha0, v0);
    if(p1) acc8(la1, ha1, v1);
    if(p2) acc8(la2, ha2, v2);
    if(p3) acc8(la3, ha3, v3);
  }
  float4 lo, hi;
  lo.x = (la0.x+la1.x)+(la2.x+la3.x); lo.y = (la0.y+la1.y)+(la2.y+la3.y);
  lo.z = (la0.z+la1.z)+(la2.z+la3.z); lo.w = (la0.w+la1.w)+(la2.w+la3.w);
  hi.x = (ha0.x+ha1.x)+(ha2.x+ha3.x); hi.y = (ha0.y+ha1.y)+(ha2.y+ha3.y);
  hi.z = (ha0.z+ha1.z)+(ha2.z+ha3.z); hi.w = (ha0.w+ha1.w)+(ha2.w+ha3.w);
  float4 L1,H1,L2,H2,L3,H3,L4,H4,L5,H5;
  #define SH4(dst,src,off) dst.x=__shfl(src.x,lane+off,64); dst.y=__shfl(src.y,lane+off,64); \
                           dst.z=__shfl(src.z,lane+off,64); dst.w=__shfl(src.w,lane+off,64);
  SH4(L1,lo,10) SH4(H1,hi,10)
  SH4(L2,lo,20) SH4(H2,hi,20)
  SH4(L3,lo,30) SH4(H3,hi,30)
  SH4(L4,lo,40) SH4(H4,hi,40)
  SH4(L5,lo,50) SH4(H5,hi,50)
  #undef SH4
  if(lane < 10){
    float4 tl, th;
    tl.x = ((lo.x+L1.x)+(L2.x+L3.x))+(L4.x+L5.x);
    tl.y = ((lo.y+L1.y)+(L2.y+L3.y))+(L4.y+L5.y);
    tl.z = ((lo.z+L1.z)+(L2.z+L3.z))+(L4.z+L5.z);
    tl.w = ((lo.w+L1.w)+(L2.w+L3.w))+(L4.w+L5.w);
    th.x = ((hi.x+H1.x)+(H2.x+H3.x))+(H4.x+H5.x);
    th.y = ((hi.y+H1.y)+(H2.y+H3.y))+(H4.y+H5.y);
    th.z = ((hi.z+H1.z)+(H2.z+H3.z))+(H4.z+H5.z);
    th.w = ((hi.w+H1.w)+(H2.w+H3.w))+(H4.w+H5.w);
    int d = r1 - r0;
    int dbase = part*8;
    if(d > 0){
      float inv = 1.f/(float)d;
      tl.x*=inv; tl.y*=inv; tl.z*=inv; tl.w*=inv;
      th.x*=inv; th.y*=inv; th.z*=inv; th.w*=inv;
    } else {
      const float* fr = feat + (size_t)wid*DIN;   // exact fallback
      tl.x = (dbase+0 < DIN) ? fr[dbase+0] : 0.f;
      tl.y = (dbase+1 < DIN) ? fr[dbase+1] : 0.f;
      tl.z = (dbase+2 < DIN) ? fr[dbase+2] : 0.f;
      tl.w = (dbase+3 < DIN) ? fr[dbase+3] : 0.f;
      th.x = (dbase+4 < DIN) ? fr[dbase+4] : 0.f;
      th.y = (dbase+5 < DIN) ? fr[dbase+5] : 0.f;
      th.z = (dbase+6 < DIN) ? fr[dbase+6] : 0.f;
      th.w = (dbase+7 < DIN) ? fr[dbase+7] : 0.f;
    }
    uint4 o;
    o.x = (uint)f2bf(tl.x) | ((uint)f2bf(tl.y) << 16);
    o.y = (uint)f2bf(tl.z) | ((uint)f2bf(tl.w) << 16);
    o.z = (uint)f2bf(th.x) | ((uint)f2bf(th.y) << 16);
    o.w = (uint)f2bf(th.z) | ((uint)f2bf(th.w) << 16);
    *(uint4*)&outb[(size_t)wid*DPAD + dbase] = o;
  }
}

// ---------------- fused GCN linear layers: y2 = relu(agg@W1+b1)@W2 ----------
__global__ __launch_bounds__(256) void k_gcn12(const ushort* __restrict__ Ab80,
      const ushort* __restrict__ W1tb, const ushort* __restrict__ W2tb,
      const float* __restrict__ b1, ushort* __restrict__ y2b){
  __shared__ ushort L[24960];      // 49920 B union
  ushort* As  = L;                 // [128][104] phase1
  ushort* Ws  = L + 128*104;       // [112][104] phase1
  ushort* Hs  = L;                 // [128][136] phase2
  ushort* W2s = L + 128*136;       // [32][136]  phase2
  int tid = threadIdx.x;
  int n0 = blockIdx.x*128;
  #pragma unroll
  for(int p=0;p<5;p++){
    int idx = tid + p*256;
    int row = idx/10, c = (idx - row*10)*8;
    uint4 v = {0,0,0,0};
    if(n0+row < NN) v = *(const uint4*)&Ab80[(size_t)(n0+row)*DPAD + c];
    *(uint4*)&As[row*104 + c] = v;
  }
  { int row = tid>>1, c = 80 + (tid&1)*8;
    *(uint4*)&As[row*104 + c] = (uint4){0,0,0,0}; }
  #pragma unroll
  for(int p=0;p<6;p++){
    int idx = tid + p*256;
    if(idx < 1344){
      int row = idx/12, c = (idx - row*12)*8;
      *(uint4*)&Ws[row*104 + c] = *(const uint4*)&W1tb[row*96 + c];
    }
  }
  __syncthreads();
  int lane = tid & 63, w = tid >> 6;
  int wm = w*32;
  int frow = lane & 15, fk = (lane>>4)*8;
  f32x4 acc[2][7];
  #pragma unroll
  for(int a=0;a<2;a++)
    #pragma unroll
    for(int b=0;b<7;b++) acc[a][b] = (f32x4){0.f,0.f,0.f,0.f};
  #pragma unroll
  for(int ks=0; ks<3; ks++){
    bf16x8 af[2], bfr[7];
    #pragma unroll
    for(int mt=0;mt<2;mt++) af[mt] = *(const bf16x8*)&As[(wm+mt*16+frow)*104 + ks*32 + fk];
    #pragma unroll
    for(int nt=0;nt<7;nt++) bfr[nt] = *(const bf16x8*)&Ws[(nt*16+frow)*104 + ks*32 + fk];
    #pragma unroll
    for(int mt=0;mt<2;mt++)
      #pragma unroll
      for(int nt=0;nt<7;nt++)
        acc[mt][nt] = __builtin_amdgcn_mfma_f32_16x16x32_bf16(af[mt], bfr[nt], acc[mt][nt], 0, 0, 0);
  }
  int crow = (lane>>4)*4, ccol = lane & 15;
  float bv[7];
  #pragma unroll
  for(int nt=0;nt<7;nt++){
    int c = nt*16 + ccol;
    bv[nt] = (c < DH1) ? b1[c] : 0.f;
  }
  __syncthreads();
  #pragma unroll
  for(int mt=0;mt<2;mt++)
    #pragma unroll
    for(int nt=0;nt<7;nt++)
      #pragma unroll
      for(int rr=0;rr<4;rr++)
        Hs[(wm + mt*16 + crow + rr)*136 + nt*16 + ccol] =
            f2bf(fmaxf(acc[mt][nt][rr] + bv[nt], 0.f));
  { int row = tid>>1, c = 112 + (tid&1)*8;
    *(uint4*)&Hs[row*136 + c] = (uint4){0,0,0,0}; }
  #pragma unroll
  for(int p=0;p<2;p++){
    int idx = tid + p*256;
    int row = idx >> 4, c = (idx & 15)*8;
    *(uint4*)&W2s[row*136 + c] = *(const uint4*)&W2tb[row*128 + c];
  }
  __syncthreads();
  f32x4 acc2[2][2];
  #pragma unroll
  for(int a=0;a<2;a++){ acc2[a][0]=(f32x4){0,0,0,0}; acc2[a][1]=(f32x4){0,0,0,0}; }
  #pragma unroll
  for(int ks=0; ks<4; ks++){
    bf16x8 af2[2], bf2r[2];
    #pragma unroll
    for(int mt=0;mt<2;mt++) af2[mt] = *(const bf16x8*)&Hs[(wm+mt*16+frow)*136 + ks*32 + fk];
    #pragma unroll
    for(int nt=0;nt<2;nt++) bf2r[nt] = *(const bf16x8*)&W2s[(nt*16+frow)*136 + ks*32 + fk];
    #pragma unroll
    for(int mt=0;mt<2;mt++)
      #pragma unroll
      for(int nt=0;nt<2;nt++)
        acc2[mt][nt] = __builtin_amdgcn_mfma_f32_16x16x32_bf16(af2[mt], bf2r[nt], acc2[mt][nt], 0, 0, 0);
  }
  #pragma unroll
  for(int mt=0;mt<2;mt++)
    #pragma unroll
    for(int nt=0;nt<2;nt++)
      #pragma unroll
      for(int rr=0;rr<4;rr++){
        int col = nt*16 + ccol;
        int r = n0 + wm + mt*16 + crow + rr;
        if(col < DGD && r < NN)
          y2b[(size_t)r*DGD + col] = f2bf(acc2[mt][nt][rr]);
      }
}

// agg2: uint2 gathers (4 dims), 12 edges x 5 lanes, 48-edge window, no atomics
__global__ void k_agg2d(const ushort* __restrict__ y2b, const int* __restrict__ rowptr,
                        const int* __restrict__ adj, const float* __restrict__ b2,
                        float* __restrict__ y3){
  int wid  = (blockIdx.x*blockDim.x + threadIdx.x) >> 6;
  int lane = threadIdx.x & 63;
  if(wid >= NN) return;
  int r0 = rowptr[wid], r1 = rowptr[wid+1];
  int eo = lane / 5;
  int part = lane - eo*5;
  bool act = lane < 60;
  if(!act){ eo = 0; part = 0; }
  float4 a0={0,0,0,0}, a1={0,0,0,0}, a2={0,0,0,0}, a3={0,0,0,0};
  for(int j = r0; j < r1; j += 48){
    int j0 = j + eo, j1 = j + 12 + eo, j2 = j + 24 + eo, j3 = j + 36 + eo;
    bool p0 = act && (j0 < r1), p1 = act && (j1 < r1);
    bool p2 = act && (j2 < r1), p3 = act && (j3 < r1);
    int s0 = adj[p0 ? j0 : r0];
    int s1 = adj[p1 ? j1 : r0];
    int s2 = adj[p2 ? j2 : r0];
    int s3 = adj[p3 ? j3 : r0];
    uint2 v0 = *(const uint2*)&y2b[(size_t)s0*DGD + part*4];
    uint2 v1 = *(const uint2*)&y2b[(size_t)s1*DGD + part*4];
    uint2 v2 = *(const uint2*)&y2b[(size_t)s2*DGD + part*4];
    uint2 v3 = *(const uint2*)&y2b[(size_t)s3*DGD + part*4];
    if(p0){ acc2u(*(float2*)&a0.x, v0.x); acc2u(*(float2*)&a0.z, v0.y); }
    if(p1){ acc2u(*(float2*)&a1.x, v1.x); acc2u(*(float2*)&a1.z, v1.y); }
    if(p2){ acc2u(*(float2*)&a2.x, v2.x); acc2u(*(float2*)&a2.z, v2.y); }
    if(p3){ acc2u(*(float2*)&a3.x, v3.x); acc2u(*(float2*)&a3.z, v3.y); }
  }
  float4 t;
  t.x = (a0.x+a1.x)+(a2.x+a3.x);
  t.y = (a0.y+a1.y)+(a2.y+a3.y);
  t.z = (a0.z+a1.z)+(a2.z+a3.z);
  t.w = (a0.w+a1.w)+(a2.w+a3.w);
  t.x += __shfl(t.x, lane+30, 64); t.y += __shfl(t.y, lane+30, 64);
  t.z += __shfl(t.z, lane+30, 64); t.w += __shfl(t.w, lane+30, 64);
  t.x += __shfl(t.x, lane+15, 64); t.y += __shfl(t.y, lane+15, 64);
  t.z += __shfl(t.z, lane+15, 64); t.w += __shfl(t.w, lane+15, 64);
  float ux = __shfl(t.x, lane+5, 64),  uy = __shfl(t.y, lane+5, 64);
  float uz = __shfl(t.z, lane+5, 64),  uw = __shfl(t.w, lane+5, 64);
  float wx = __shfl(t.x, lane+10, 64), wy = __shfl(t.y, lane+10, 64);
  float wz = __shfl(t.z, lane+10, 64), ww = __shfl(t.w, lane+10, 64);
  if(lane < 5){
    float tx = t.x + ux + wx, ty = t.y + uy + wy;
    float tz = t.z + uz + wz, tw = t.w + uw + ww;
    int d = r1 - r0;
    float bx, by, bz, bw;
    if(d > 0){
      float inv = 1.f/(float)d;
      bx = tx*inv; by = ty*inv; bz = tz*inv; bw = tw*inv;
    } else {
      uint2 v = *(const uint2*)&y2b[(size_t)wid*DGD + lane*4];
      bx = __uint_as_float(v.x << 16);
      by = __uint_as_float(v.x & 0xffff0000u);
      bz = __uint_as_float(v.y << 16);
      bw = __uint_as_float(v.y & 0xffff0000u);
    }
    float4 o;
    o.x = fmaxf(bx + b2[lane*4+0], 0.f);
    o.y = fmaxf(by + b2[lane*4+1], 0.f);
    o.z = fmaxf(bz + b2[lane*4+2], 0.f);
    o.w = fmaxf(bw + b2[lane*4+3], 0.f);
    *(float4*)&y3[(size_t)wid*DGD + lane*4] = o;
  }
}

// head3: per-graph mean + attention softmax + DIRECT A' row write (bf16)
__global__ __launch_bounds__(256) void k_head3(const float* __restrict__ y3,
      const int* __restrict__ gofs, const float* __restrict__ Wat,
      const float* __restrict__ desc2d, ushort* __restrict__ Ab){
  int g = blockIdx.x, t = threadIdx.x;
  int n0 = gofs[g], n1 = gofs[g+1];
  int cnt = n1 - n0;
  __shared__ float part[240];
  __shared__ float hgaL[21];
  __shared__ float daaL[201];
  __shared__ float red[256];
  if(t < 240){
    int grp = t/20, dim = t - grp*20;
    float a = 0.f;
    for(int n = n0 + grp; n < n1; n += 12) a += y3[(size_t)n*DGD + dim];
    part[t] = a;
  }
  __syncthreads();
  if(t < DGD){
    float s = 0.f;
    #pragma unroll
    for(int k=0;k<12;k++) s += part[k*20 + t];
    hgaL[t] = s / (float)max(cnt, 1);
  }
  if(t == DGD) hgaL[20] = 1.f;
  __syncthreads();
  float logit = 0.f;
  if(t < DD2){
    #pragma unroll
    for(int k=0;k<DGD;k++) logit += hgaL[k]*Wat[k*DD2 + t];
  }
  float v = (t < DD2) ? logit : -1e30f;
  red[t] = v; __syncthreads();
  for(int off=128; off>=1; off>>=1){ if(t<off) red[t]=fmaxf(red[t],red[t+off]); __syncthreads(); }
  float mx = red[0]; __syncthreads();
  float e = (t < DD2) ? expf(logit - mx) : 0.f;
  red[t] = e; __syncthreads();
  for(int off=128; off>=1; off>>=1){ if(t<off) red[t]+=red[t+off]; __syncthreads(); }
  float s = red[0];
  if(t < DD2) daaL[t] = (e/s)*desc2d[(size_t)g*DD2 + t];
  if(t == DD2) daaL[200] = 1.f;
  __syncthreads();
  ushort* arow = Ab + (size_t)g*KPAD;
  #pragma unroll
  for(int p=0;p<17;p++){
    int k = t + 256*p;
    ushort o = 0;
    if(k < 4221){
      int i = (int)(((uint)k * 83470u) >> 24);   // floor(k/201), exact for k<4221
      int j = k - i*201;
      o = f2bf(hgaL[i]*daaL[j]);
    }
    arow[k] = o;
  }
}

// ---------------- fusion GEMM v6: single-B bf16, M-tile 64, grid (64,8) -----
__global__ __launch_bounds__(256) void k_fuse6(const ushort* __restrict__ Ab,
                                               const ushort* __restrict__ Bthi,
                                               float* __restrict__ zp){
  __shared__ ushort Al[64][40];
  __shared__ ushort Bl[128][40];
  int tid = threadIdx.x;
  int m0 = blockIdx.x * 64;
  int seg = blockIdx.y;
  int lane = tid & 63;
  int w = tid >> 6;
  int wm = (w >> 1) * 32;
  int wn = (w & 1) * 64;
  f32x4 acc[2][4];
  #pragma unroll
  for(int a=0;a<2;a++)
    #pragma unroll
    for(int b=0;b<4;b++) acc[a][b] = (f32x4){0.f,0.f,0.f,0.f};

  int ar = tid >> 2;
  int as = (tid & 3) * 8;
  int br = tid >> 1;
  int bs = (tid & 1) * 16;
  const uint4* gA = (const uint4*)(Ab   + (size_t)(m0 + ar)*KPAD + seg*KSEG + as);
  const uint4* gB = (const uint4*)(Bthi + (size_t)br*KPAD + seg*KSEG + bs);

  int frow = lane & 15;
  int fk   = (lane >> 4) * 8;

  for(int ks=0; ks<17; ks++){
    uint4 va = gA[0];
    uint4 vb0 = gB[0], vb1 = gB[1];
    gA += 4; gB += 4;                // one k-step = 32 shorts = 4 uint4
    __syncthreads();
    *(uint4*)&Al[ar][as]   = va;
    *(uint4*)&Bl[br][bs]   = vb0;
    *(uint4*)&Bl[br][bs+8] = vb1;
    __syncthreads();
    bf16x8 af[2], bh[4];
    #pragma unroll
    for(int mt=0;mt<2;mt++) af[mt] = *(const bf16x8*)&Al[wm + mt*16 + frow][fk];
    #pragma unroll
    for(int nt=0;nt<4;nt++) bh[nt] = *(const bf16x8*)&Bl[wn + nt*16 + frow][fk];
    #pragma unroll
    for(int mt=0;mt<2;mt++)
      #pragma unroll
      for(int nt=0;nt<4;nt++)
        acc[mt][nt] = __builtin_amdgcn_mfma_f32_16x16x32_bf16(af[mt], bh[nt], acc[mt][nt], 0, 0, 0);
  }
  float* zb = zp + ((size_t)seg*NB + m0)*128;
  int drow = (lane >> 4) * 4;
  int dcol = lane & 15;
  #pragma unroll
  for(int mt=0;mt<2;mt++)
    #pragma unroll
    for(int nt=0;nt<4;nt++)
      #pragma unroll
      for(int rr=0;rr<4;rr++)
        zb[(size_t)(wm + mt*16 + drow + rr)*128 + wn + nt*16 + dcol] = acc[mt][nt][rr];
}

__global__ void k_reduce(const float* __restrict__ zp, const float* __restrict__ b1,
                         float* __restrict__ z1){
  int idx = blockIdx.x*256 + threadIdx.x;
  if(idx >= NB*32) return;
  const float4* z = (const float4*)zp;
  float4 o = ((const float4*)b1)[idx & 31];
  #pragma unroll
  for(int s=0;s<NSEG;s++){
    float4 a = z[idx + (size_t)s*NB*32];
    o.x += a.x; o.y += a.y; o.z += a.z; o.w += a.w;
  }
  ((float4*)z1)[idx] = o;
}

// BN stats -> folded scale/shift
__global__ void k_bnstats(const float* __restrict__ X, int C,
                          const float* __restrict__ gamma, const float* __restrict__ beta,
                          float* __restrict__ scale, float* __restrict__ shift){
  int c = blockIdx.x;
  float s=0.f, s2=0.f;
  for(int r=threadIdx.x; r<NB; r+=256){
    float v = X[(size_t)r*C + c];
    s += v; s2 += v*v;
  }
  __shared__ float sh[256], sh2[256];
  sh[threadIdx.x]=s; sh2[threadIdx.x]=s2;
  __syncthreads();
  for(int off=128; off>=1; off>>=1){
    if(threadIdx.x<off){ sh[threadIdx.x]+=sh[threadIdx.x+off]; sh2[threadIdx.x]+=sh2[threadIdx.x+off]; }
    __syncthreads();
  }
  if(threadIdx.x==0){
    float mu  = sh[0]*(1.0f/NB);
    float var = sh2[0]*(1.0f/NB) - mu*mu;
    float a = gamma[c]*rsqrtf(var + 1e-5f);
    scale[c] = a;
    shift[c] = beta[c] - mu*a;
  }
}

__global__ void k_mlp2(const float* __restrict__ z1, const float* __restrict__ sc,
                       const float* __restrict__ sf, const float* __restrict__ W,
                       const float* __restrict__ bias, float* __restrict__ out){
  __shared__ float Wl[DM1*DM2];
  __shared__ float scl[DM1], sfl[DM1];
  for(int idx=threadIdx.x; idx<DM1*DM2; idx+=256) Wl[idx] = W[idx];
  if(threadIdx.x < DM1){ scl[threadIdx.x]=sc[threadIdx.x]; sfl[threadIdx.x]=sf[threadIdx.x]; }
  __syncthreads();
  int idx = blockIdx.x*256 + threadIdx.x;
  int r = idx >> 5, o = idx & 31;
  if(r >= NB) return;
  float acc = bias[o];
  const float* xr = z1 + (size_t)r*DM1;
  for(int k=0;k<DM1;k++){
    float xn = fmaxf(xr[k]*scl[k] + sfl[k], 0.f);
    acc += xn * Wl[k*DM2 + o];
  }
  out[(size_t)r*DM2 + o] = acc;
}

__global__ void k_final(const float* __restrict__ z2, const float* __restrict__ sc2,
                        const float* __restrict__ sf2, const float* __restrict__ W3,
                        const float* __restrict__ b3, float* __restrict__ out){
  int r = blockIdx.x*256 + threadIdx.x;
  if(r >= NB) return;
  float acc = b3[0];
  const float* xr = z2 + (size_t)r*DM2;
  #pragma unroll
  for(int o=0;o<DM2;o++){
    float xn = fmaxf(xr[o]*sc2[o] + sf2[o], 0.f);
    acc += xn * W3[o];
  }
  out[r] = acc;
}

extern "C" void kernel_launch(void* const* d_in, const int* in_sizes, int n_in,
                              void* d_out, int out_size, void* d_ws, size_t ws_size,
                              hipStream_t stream){
  (void)in_sizes; (void)n_in; (void)out_size; (void)ws_size;
  const float* feat   = (const float*)d_in[0];
  const float* desc2d = (const float*)d_in[1];
  const int*   esrc   = (const int*)d_in[3];
  const int*   edst   = (const int*)d_in[4];
  const int*   gid    = (const int*)d_in[5];
  const float* Wg1    = (const float*)d_in[6];
  const float* bg1    = (const float*)d_in[7];
  const float* Wg2    = (const float*)d_in[8];
  const float* bg2    = (const float*)d_in[9];
  const float* Wat    = (const float*)d_in[10];
  const float* Wf1    = (const float*)d_in[11];
  const float* bf1    = (const float*)d_in[12];
  const float* Wf2    = (const float*)d_in[13];
  const float* bf2    = (const float*)d_in[14];
  const float* Wf3    = (const float*)d_in[15];
  const float* bf3    = (const float*)d_in[16];
  const float* gamma1 = (const float*)d_in[17];
  const float* beta1  = (const float*)d_in[18];
  const float* gamma2 = (const float*)d_in[19];
  const float* beta2  = (const float*)d_in[20];
  float* out = (float*)d_out;

  char* base = (char*)d_ws;
  size_t off = 0;
  auto alloc = [&](size_t bytes)->void*{
    void* r = base + off;
    off = (off + bytes + 255) & ~(size_t)255;
    return r;
  };
  int*    rowptr = (int*)   alloc((size_t)(NN+1)*4);
  int*    gofs   = (int*)   alloc((size_t)(NB+1)*4);
  int*    adj    = (int*)   alloc((size_t)NE*4);
  int*    bukCur = (int*)   alloc((size_t)NBUK*4);
  float*  sc1    = (float*) alloc((size_t)DM1*4);
  float*  sf1    = (float*) alloc((size_t)DM1*4);
  float*  sc2    = (float*) alloc((size_t)DM2*4);
  float*  sf2    = (float*) alloc((size_t)DM2*4);
  ushort* W1thi  = (ushort*)alloc((size_t)128*KPAD*2);
  ushort* W1tb   = (ushort*)alloc((size_t)112*96*2);
  ushort* W2tb   = (ushort*)alloc((size_t)32*128*2);
  float*  z1     = (float*) alloc((size_t)NB*DM1*4);
  float*  z2     = (float*) alloc((size_t)NB*DM2*4);
  // R1 (32 MB): pairs(14.3M) -> agg80b(16M) -> zp(16.8M); y3 at +17M (8M)
  char*   R1     = (char*)  alloc((size_t)NN*DPAD*4);
  // R2 (35.7 MB): featb(16M) + y2b(@16M, 4M) -> Ab(35.7M)
  char*   R2     = (char*)  alloc((size_t)NB*KPAD*2);
  uint2*  pairs  = (uint2*) R1;
  ushort* agg80b = (ushort*)R1;
  float*  zp     = (float*) R1;
  float*  y3     = (float*) (R1 + (size_t)17*1024*1024);
  ushort* featb  = (ushort*)R2;
  ushort* y2b    = (ushort*)(R2 + (size_t)NN*DPAD*2);
  ushort* Ab     = (ushort*)R2;

  hipMemsetAsync(bukCur, 0, (size_t)NBUK*4, stream);

  k_pre <<<PRE_BUK + PRE_PREP + PRE_CVT, 256, 0, stream>>>(
      esrc, edst, bukCur, pairs, Wf1, W1thi, Wg1, W1tb, Wg2, W2tb, feat, featb);
  k_csr2<<<NBUK + GOFS_BLKS, 512, 0, stream>>>(pairs, bukCur, rowptr, adj, gid, gofs);

  k_agg1e <<<(NN+3)/4, 256, 0, stream>>>(featb, feat, rowptr, adj, agg80b);
  k_gcn12 <<<(NN+127)/128, 256, 0, stream>>>(agg80b, W1tb, W2tb, bg1, y2b);
  k_agg2d <<<(NN+3)/4, 256, 0, stream>>>(y2b, rowptr, adj, bg2, y3);

  k_head3<<<NB, 256, 0, stream>>>(y3, gofs, Wat, desc2d, Ab);
  k_fuse6<<<dim3(64, NSEG), 256, 0, stream>>>(Ab, W1thi, zp);
  k_reduce<<<(NB*32+255)/256, 256, 0, stream>>>(zp, bf1, z1);

  k_bnstats<<<DM1, 256, 0, stream>>>(z1, DM1, gamma1, beta1, sc1, sf1);
  k_mlp2   <<<(NB*DM2)/256, 256, 0, stream>>>(z1, sc1, sf1, Wf2, bf2, z2);
  k_bnstats<<<DM2, 256, 0, stream>>>(z2, DM2, gamma2, beta2, sc2, sf2);
  k_final  <<<(NB+255)/256, 256, 0, stream>>>(z2, sc2, sf2, Wf3, bf3, out);
}

// Round 19
// 217.675 us; speedup vs baseline: 1.1429x; 1.0052x over previous
//
#include <hip/hip_runtime.h>

#define NN 100000      // nodes
#define NE 1600000     // edges
#define NB 4096        // graphs
#define DIN 74
#define DPAD 80
#define DH1 100
#define DGD 20
#define DD2 200
#define DM1 128
#define DM2 32
#define NSEG 8
#define KPAD 4352      // 4221 padded to 8*544
#define KSEG 544
#define NBUK 256
#define BNODES 391     // nodes per bucket (256*391 >= 100000)
#define CAP 7000       // per-bucket capacity (mean 6256, +9 sigma)
#define EPB 3125       // edges per bucket block (NE/512)
#define GOFS_BLKS 64
#define PRE_BUK 512
#define PRE_PREP (KPAD/32 + 2)          // 138
typedef unsigned int uint;
typedef unsigned short ushort;
typedef __attribute__((ext_vector_type(8))) short bf16x8;
typedef __attribute__((ext_vector_type(4))) float f32x4;

__device__ __forceinline__ float bf2f(ushort u){ return __uint_as_float(((uint)u)<<16); }
__device__ __forceinline__ ushort f2bf(float f){
  uint u = __float_as_uint(f);
  return (ushort)((u + 0x7fffu + ((u >> 16) & 1u)) >> 16);   // RNE
}
// floor(d/391) for d < 100096 (M=ceil(2^32/391)=10984572)
__device__ __forceinline__ uint bucket_of(int d){
  return (uint)(((unsigned long long)(uint)d * 10984572ull) >> 32);
}
__device__ __forceinline__ void acc2u(float2& a, uint v){
  a.x += __uint_as_float(v << 16);
  a.y += __uint_as_float(v & 0xffff0000u);
}
__device__ __forceinline__ void acc8(float4& a, float4& b, uint4 v){
  a.x += __uint_as_float(v.x << 16);
  a.y += __uint_as_float(v.x & 0xffff0000u);
  a.z += __uint_as_float(v.y << 16);
  a.w += __uint_as_float(v.y & 0xffff0000u);
  b.x += __uint_as_float(v.z << 16);
  b.y += __uint_as_float(v.z & 0xffff0000u);
  b.z += __uint_as_float(v.w << 16);
  b.w += __uint_as_float(v.w & 0xffff0000u);
}

// ---------------- feat -> bf16 padded [N][80] (NO LDS: full occupancy) ------
__global__ void k_cvt(const float* __restrict__ feat, ushort* __restrict__ fb){
  int idx = blockIdx.x*256 + threadIdx.x;
  if(idx < NN*DPAD){
    int row = idx / DPAD, d = idx - row*DPAD;
    fb[idx] = (d < DIN) ? f2bf(feat[(size_t)row*DIN + d]) : (ushort)0;
  }
}

// ---------------- front-end kernel: bucket sort | weight prep ----------------
__global__ __launch_bounds__(256) void k_pre(
      const int* __restrict__ src, const int* __restrict__ dst,
      int* __restrict__ bukCur, uint2* __restrict__ pairs,
      const float* __restrict__ Wf1, ushort* __restrict__ Bthi,
      const float* __restrict__ W1g, ushort* __restrict__ W1tb,
      const float* __restrict__ W2g, ushort* __restrict__ W2tb){
  __shared__ __align__(16) char SM[35360];
  int blk = blockIdx.x, tid = threadIdx.x;
  if(blk < PRE_BUK){
    // ---- CSR phase A: LDS bucket sort (256 buckets), coalesced flush ----
    uint2* stage = (uint2*)SM;               // 25000 B
    ushort* bidx = (ushort*)(SM + 25000);    // 6250 B
    int* cnt   = (int*)(SM + 31252);         // 1024 B
    int* scanv = (int*)(SM + 32276);         // 1024 B
    int* gadj  = (int*)(SM + 33300);         // 1024 B
    int* cur   = (int*)(SM + 34324);         // 1024 B
    cnt[tid] = 0;                            // NBUK == blockDim == 256
    __syncthreads();
    int e0 = blk * EPB;
    for(int i = tid; i < EPB; i += 256)
      atomicAdd(&cnt[bucket_of(dst[e0 + i])], 1);
    __syncthreads();
    int c = cnt[tid];
    scanv[tid] = c;
    __syncthreads();
    for(int off=1; off<NBUK; off<<=1){
      int v = (tid >= off) ? scanv[tid-off] : 0;
      __syncthreads();
      scanv[tid] += v;
      __syncthreads();
    }
    int excl = scanv[tid] - c;
    int base = atomicAdd(&bukCur[tid], c);
    gadj[tid] = tid*CAP + base - excl;
    cur[tid]  = excl;
    __syncthreads();
    for(int i = tid; i < EPB; i += 256){
      int d = dst[e0 + i];
      int s = src[e0 + i];
      uint b = bucket_of(d);
      int p = atomicAdd(&cur[b], 1);
      stage[p] = make_uint2((uint)s, (uint)d);
      bidx[p] = (ushort)b;
    }
    __syncthreads();
    for(int i = tid; i < EPB; i += 256)
      pairs[(size_t)gadj[bidx[i]] + i] = stage[i];
  } else if(blk < PRE_BUK + KPAD/32){
    // ---- fusion W1 -> bf16 transposed [128][KPAD] ----
    float (*Wl)[128] = (float(*)[128])SM;    // 16 KB
    int k0 = (blk - PRE_BUK) * 32;
    for(int idx=tid; idx<32*128; idx+=256){
      int kk = idx >> 7, n = idx & 127;
      int k = k0 + kk;
      Wl[kk][n] = (k < 4221) ? Wf1[(size_t)k*128 + n] : 0.f;
    }
    __syncthreads();
    int n = tid >> 1, kh = (tid & 1) * 16;
    uint ph[8];
    #pragma unroll
    for(int e=0;e<8;e++){
      ushort h0 = f2bf(Wl[kh+2*e][n]);
      ushort h1 = f2bf(Wl[kh+2*e+1][n]);
      ph[e] = (uint)h0 | ((uint)h1 << 16);
    }
    uint4* dh = (uint4*)(Bthi + (size_t)n*KPAD + k0 + kh);
    dh[0] = make_uint4(ph[0],ph[1],ph[2],ph[3]);
    dh[1] = make_uint4(ph[4],ph[5],ph[6],ph[7]);
  } else if(blk == PRE_BUK + KPAD/32){
    for(int idx = tid; idx < 112*96; idx += 256){
      int n = idx / 96, k = idx - n*96;
      float v = (n < DH1 && k < DIN) ? W1g[(size_t)k*DH1 + n] : 0.f;
      W1tb[idx] = f2bf(v);
    }
  } else {
    for(int idx = tid; idx < 32*128; idx += 256){
      int n = idx >> 7, k = idx & 127;
      float v = (n < DGD && k < DH1) ? W2g[(size_t)k*DGD + n] : 0.f;
      W2tb[idx] = f2bf(v);
    }
  }
}

// ---------------- CSR phase B (256 blocks) + parallel gofs scatter ----------
__global__ __launch_bounds__(512) void k_csr2(const uint2* __restrict__ pairs,
      const int* __restrict__ bukTot, int* __restrict__ rowptr, int* __restrict__ adj,
      const int* __restrict__ gid, int* __restrict__ gofs){
  if(blockIdx.x >= NBUK){
    // gofs[g] = lower_bound(gid, g): boundary scatter over sorted gid
    int t0 = (blockIdx.x - NBUK)*512 + threadIdx.x;
    for(int i = t0; i <= NN; i += GOFS_BLKS*512){
      int prev = (i == 0) ? -1 : gid[i-1];
      int cur  = (i < NN) ? gid[i] : NB;
      for(int g = prev+1; g <= cur; g++) gofs[g] = i;
    }
    return;
  }
  __shared__ int degL[BNODES];
  __shared__ int curL[BNODES];
  __shared__ int csum[NBUK];
  __shared__ int tsum[512];
  int b = blockIdx.x, tid = threadIdx.x;
  if(tid < NBUK) csum[tid] = bukTot[tid];
  __syncthreads();
  for(int off=1; off<NBUK; off<<=1){
    int v = (tid < NBUK && tid >= off) ? csum[tid-off] : 0;
    __syncthreads();
    if(tid < NBUK) csum[tid] += v;
    __syncthreads();
  }
  int gbase = (b == 0) ? 0 : csum[b-1];
  int tot = bukTot[b];
  int d0 = b*BNODES;
  int nloc = min(BNODES, NN - d0);
  for(int i=tid;i<nloc;i+=512){ degL[i]=0; curL[i]=0; }
  __syncthreads();
  const uint2* pb = pairs + (size_t)b*CAP;
  for(int i=tid;i<tot;i+=512)
    atomicAdd(&degL[(int)pb[i].y - d0], 1);
  __syncthreads();
  int s = (tid < nloc) ? degL[tid] : 0;
  tsum[tid] = s;
  __syncthreads();
  for(int off=1; off<512; off<<=1){
    int v = (tid >= off) ? tsum[tid-off] : 0;
    __syncthreads();
    tsum[tid] += v;
    __syncthreads();
  }
  int excl = tsum[tid] - s;
  if(tid < nloc){
    degL[tid] = excl;
    rowptr[d0 + tid] = gbase + excl;
  }
  if(b == NBUK-1 && tid == 0) rowptr[NN] = gbase + tot;
  __syncthreads();
  for(int i=tid;i<tot;i+=512){
    uint2 pr = pb[i];
    int dl = (int)pr.y - d0;
    int pos = atomicAdd(&curL[dl],1);
    adj[gbase + degL[dl] + pos] = (int)pr.x;
  }
}

// ---------------- GCN layer 1 mean-agg: uint4 gathers, 6 edges x 10 lanes ---
__global__ void k_agg1e(const ushort* __restrict__ fb, const float* __restrict__ feat,
                        const int* __restrict__ rowptr, const int* __restrict__ adj,
                        ushort* __restrict__ outb){
  int wid  = (blockIdx.x*blockDim.x + threadIdx.x) >> 6;
  int lane = threadIdx.x & 63;
  if(wid >= NN) return;
  int r0 = rowptr[wid], r1 = rowptr[wid+1];
  int eo = lane / 10;
  int part = lane - eo*10;
  bool act = lane < 60;
  if(!act){ eo = 0; part = 0; }
  float4 la0={0,0,0,0}, ha0={0,0,0,0}, la1={0,0,0,0}, ha1={0,0,0,0};
  float4 la2={0,0,0,0}, ha2={0,0,0,0}, la3={0,0,0,0}, ha3={0,0,0,0};
  for(int j = r0; j < r1; j += 24){
    int j0 = j + eo, j1 = j + 6 + eo, j2 = j + 12 + eo, j3 = j + 18 + eo;
    bool p0 = act && (j0 < r1), p1 = act && (j1 < r1);
    bool p2 = act && (j2 < r1), p3 = act && (j3 < r1);
    int s0 = adj[p0 ? j0 : r0];
    int s1 = adj[p1 ? j1 : r0];
    int s2 = adj[p2 ? j2 : r0];
    int s3 = adj[p3 ? j3 : r0];
    uint4 v0 = *(const uint4*)&fb[(size_t)s0*DPAD + part*8];
    uint4 v1 = *(const uint4*)&fb[(size_t)s1*DPAD + part*8];
    uint4 v2 = *(const uint4*)&fb[(size_t)s2*DPAD + part*8];
    uint4 v3 = *(const uint4*)&fb[(size_t)s3*DPAD + part*8];
    if(p0) acc8(la0, ha0, v0);
    if(p1) acc8(la1, ha1, v1);
    if(p2) acc8(la2, ha2, v2);
    if(p3) acc8(la3, ha3, v3);
  }
  float4 lo, hi;
  lo.x = (la0.x+la1.x)+(la2.x+la3.x); lo.y = (la0.y+la1.y)+(la2.y+la3.y);
  lo.z = (la0.z+la1.z)+(la2.z+la3.z); lo.w = (la0.w+la1.w)+(la2.w+la3.w);
  hi.x = (ha0.x+ha1.x)+(ha2.x+ha3.x); hi.y = (ha0.y+ha1.y)+(ha2.y+ha3.y);
  hi.z = (ha0.z+ha1.z)+(ha2.z+ha3.z); hi.w = (ha0.w+ha1.w)+(ha2.w+ha3.w);
  float4 L1,H1,L2,H2,L3,H3,L4,H4,L5,H5;
  #define SH4(dst,src,off) dst.x=__shfl(src.x,lane+off,64); dst.y=__shfl(src.y,lane+off,64); \
                           dst.z=__shfl(src.z,lane+off,64); dst.w=__shfl(src.w,lane+off,64);
  SH4(L1,lo,10) SH4(H1,hi,10)
  SH4(L2,lo,20) SH4(H2,hi,20)
  SH4(L3,lo,30) SH4(H3,hi,30)
  SH4(L4,lo,40) SH4(H4,hi,40)
  SH4(L5,lo,50) SH4(H5,hi,50)
  #undef SH4
  if(lane < 10){
    float4 tl, th;
    tl.x = ((lo.x+L1.x)+(L2.x+L3.x))+(L4.x+L5.x);
    tl.y = ((lo.y+L1.y)+(L2.y+L3.y))+(L4.y+L5.y);
    tl.z = ((lo.z+L1.z)+(L2.z+L3.z))+(L4.z+L5.z);
    tl.w = ((lo.w+L1.w)+(L2.w+L3.w))+(L4.w+L5.w);
    th.x = ((hi.x+H1.x)+(H2.x+H3.x))+(H4.x+H5.x);
    th.y = ((hi.y+H1.y)+(H2.y+H3.y))+(H4.y+H5.y);
    th.z = ((hi.z+H1.z)+(H2.z+H3.z))+(H4.z+H5.z);
    th.w = ((hi.w+H1.w)+(H2.w+H3.w))+(H4.w+H5.w);
    int d = r1 - r0;
    int dbase = part*8;
    if(d > 0){
      float inv = 1.f/(float)d;
      tl.x*=inv; tl.y*=inv; tl.z*=inv; tl.w*=inv;
      th.x*=inv; th.y*=inv; th.z*=inv; th.w*=inv;
    } else {
      const float* fr = feat + (size_t)wid*DIN;   // exact fallback
      tl.x = (dbase+0 < DIN) ? fr[dbase+0] : 0.f;
      tl.y = (dbase+1 < DIN) ? fr[dbase+1] : 0.f;
      tl.z = (dbase+2 < DIN) ? fr[dbase+2] : 0.f;
      tl.w = (dbase+3 < DIN) ? fr[dbase+3] : 0.f;
      th.x = (dbase+4 < DIN) ? fr[dbase+4] : 0.f;
      th.y = (dbase+5 < DIN) ? fr[dbase+5] : 0.f;
      th.z = (dbase+6 < DIN) ? fr[dbase+6] : 0.f;
      th.w = (dbase+7 < DIN) ? fr[dbase+7] : 0.f;
    }
    uint4 o;
    o.x = (uint)f2bf(tl.x) | ((uint)f2bf(tl.y) << 16);
    o.y = (uint)f2bf(tl.z) | ((uint)f2bf(tl.w) << 16);
    o.z = (uint)f2bf(th.x) | ((uint)f2bf(th.y) << 16);
    o.w = (uint)f2bf(th.z) | ((uint)f2bf(th.w) << 16);
    *(uint4*)&outb[(size_t)wid*DPAD + dbase] = o;
  }
}

// ---------------- fused GCN linear layers: y2 = relu(agg@W1+b1)@W2 ----------
__global__ __launch_bounds__(256) void k_gcn12(const ushort* __restrict__ Ab80,
      const ushort* __restrict__ W1tb, const ushort* __restrict__ W2tb,
      const float* __restrict__ b1, ushort* __restrict__ y2b){
  __shared__ ushort L[24960];      // 49920 B union
  ushort* As  = L;                 // [128][104] phase1
  ushort* Ws  = L + 128*104;       // [112][104] phase1
  ushort* Hs  = L;                 // [128][136] phase2
  ushort* W2s = L + 128*136;       // [32][136]  phase2
  int tid = threadIdx.x;
  int n0 = blockIdx.x*128;
  #pragma unroll
  for(int p=0;p<5;p++){
    int idx = tid + p*256;
    int row = idx/10, c = (idx - row*10)*8;
    uint4 v = {0,0,0,0};
    if(n0+row < NN) v = *(const uint4*)&Ab80[(size_t)(n0+row)*DPAD + c];
    *(uint4*)&As[row*104 + c] = v;
  }
  { int row = tid>>1, c = 80 + (tid&1)*8;
    *(uint4*)&As[row*104 + c] = (uint4){0,0,0,0}; }
  #pragma unroll
  for(int p=0;p<6;p++){
    int idx = tid + p*256;
    if(idx < 1344){
      int row = idx/12, c = (idx - row*12)*8;
      *(uint4*)&Ws[row*104 + c] = *(const uint4*)&W1tb[row*96 + c];
    }
  }
  __syncthreads();
  int lane = tid & 63, w = tid >> 6;
  int wm = w*32;
  int frow = lane & 15, fk = (lane>>4)*8;
  f32x4 acc[2][7];
  #pragma unroll
  for(int a=0;a<2;a++)
    #pragma unroll
    for(int b=0;b<7;b++) acc[a][b] = (f32x4){0.f,0.f,0.f,0.f};
  #pragma unroll
  for(int ks=0; ks<3; ks++){
    bf16x8 af[2], bfr[7];
    #pragma unroll
    for(int mt=0;mt<2;mt++) af[mt] = *(const bf16x8*)&As[(wm+mt*16+frow)*104 + ks*32 + fk];
    #pragma unroll
    for(int nt=0;nt<7;nt++) bfr[nt] = *(const bf16x8*)&Ws[(nt*16+frow)*104 + ks*32 + fk];
    #pragma unroll
    for(int mt=0;mt<2;mt++)
      #pragma unroll
      for(int nt=0;nt<7;nt++)
        acc[mt][nt] = __builtin_amdgcn_mfma_f32_16x16x32_bf16(af[mt], bfr[nt], acc[mt][nt], 0, 0, 0);
  }
  int crow = (lane>>4)*4, ccol = lane & 15;
  float bv[7];
  #pragma unroll
  for(int nt=0;nt<7;nt++){
    int c = nt*16 + ccol;
    bv[nt] = (c < DH1) ? b1[c] : 0.f;
  }
  __syncthreads();
  #pragma unroll
  for(int mt=0;mt<2;mt++)
    #pragma unroll
    for(int nt=0;nt<7;nt++)
      #pragma unroll
      for(int rr=0;rr<4;rr++)
        Hs[(wm + mt*16 + crow + rr)*136 + nt*16 + ccol] =
            f2bf(fmaxf(acc[mt][nt][rr] + bv[nt], 0.f));
  { int row = tid>>1, c = 112 + (tid&1)*8;
    *(uint4*)&Hs[row*136 + c] = (uint4){0,0,0,0}; }
  #pragma unroll
  for(int p=0;p<2;p++){
    int idx = tid + p*256;
    int row = idx >> 4, c = (idx & 15)*8;
    *(uint4*)&W2s[row*136 + c] = *(const uint4*)&W2tb[row*128 + c];
  }
  __syncthreads();
  f32x4 acc2[2][2];
  #pragma unroll
  for(int a=0;a<2;a++){ acc2[a][0]=(f32x4){0,0,0,0}; acc2[a][1]=(f32x4){0,0,0,0}; }
  #pragma unroll
  for(int ks=0; ks<4; ks++){
    bf16x8 af2[2], bf2r[2];
    #pragma unroll
    for(int mt=0;mt<2;mt++) af2[mt] = *(const bf16x8*)&Hs[(wm+mt*16+frow)*136 + ks*32 + fk];
    #pragma unroll
    for(int nt=0;nt<2;nt++) bf2r[nt] = *(const bf16x8*)&W2s[(nt*16+frow)*136 + ks*32 + fk];
    #pragma unroll
    for(int mt=0;mt<2;mt++)
      #pragma unroll
      for(int nt=0;nt<2;nt++)
        acc2[mt][nt] = __builtin_amdgcn_mfma_f32_16x16x32_bf16(af2[mt], bf2r[nt], acc2[mt][nt], 0, 0, 0);
  }
  #pragma unroll
  for(int mt=0;mt<2;mt++)
    #pragma unroll
    for(int nt=0;nt<2;nt++)
      #pragma unroll
      for(int rr=0;rr<4;rr++){
        int col = nt*16 + ccol;
        int r = n0 + wm + mt*16 + crow + rr;
        if(col < DGD && r < NN)
          y2b[(size_t)r*DGD + col] = f2bf(acc2[mt][nt][rr]);
      }
}

// agg2: uint2 gathers (4 dims), 12 edges x 5 lanes, 48-edge window, no atomics
__global__ void k_agg2d(const ushort* __restrict__ y2b, const int* __restrict__ rowptr,
                        const int* __restrict__ adj, const float* __restrict__ b2,
                        float* __restrict__ y3){
  int wid  = (blockIdx.x*blockDim.x + threadIdx.x) >> 6;
  int lane = threadIdx.x & 63;
  if(wid >= NN) return;
  int r0 = rowptr[wid], r1 = rowptr[wid+1];
  int eo = lane / 5;
  int part = lane - eo*5;
  bool act = lane < 60;
  if(!act){ eo = 0; part = 0; }
  float4 a0={0,0,0,0}, a1={0,0,0,0}, a2={0,0,0,0}, a3={0,0,0,0};
  for(int j = r0; j < r1; j += 48){
    int j0 = j + eo, j1 = j + 12 + eo, j2 = j + 24 + eo, j3 = j + 36 + eo;
    bool p0 = act && (j0 < r1), p1 = act && (j1 < r1);
    bool p2 = act && (j2 < r1), p3 = act && (j3 < r1);
    int s0 = adj[p0 ? j0 : r0];
    int s1 = adj[p1 ? j1 : r0];
    int s2 = adj[p2 ? j2 : r0];
    int s3 = adj[p3 ? j3 : r0];
    uint2 v0 = *(const uint2*)&y2b[(size_t)s0*DGD + part*4];
    uint2 v1 = *(const uint2*)&y2b[(size_t)s1*DGD + part*4];
    uint2 v2 = *(const uint2*)&y2b[(size_t)s2*DGD + part*4];
    uint2 v3 = *(const uint2*)&y2b[(size_t)s3*DGD + part*4];
    if(p0){ acc2u(*(float2*)&a0.x, v0.x); acc2u(*(float2*)&a0.z, v0.y); }
    if(p1){ acc2u(*(float2*)&a1.x, v1.x); acc2u(*(float2*)&a1.z, v1.y); }
    if(p2){ acc2u(*(float2*)&a2.x, v2.x); acc2u(*(float2*)&a2.z, v2.y); }
    if(p3){ acc2u(*(float2*)&a3.x, v3.x); acc2u(*(float2*)&a3.z, v3.y); }
  }
  float4 t;
  t.x = (a0.x+a1.x)+(a2.x+a3.x);
  t.y = (a0.y+a1.y)+(a2.y+a3.y);
  t.z = (a0.z+a1.z)+(a2.z+a3.z);
  t.w = (a0.w+a1.w)+(a2.w+a3.w);
  t.x += __shfl(t.x, lane+30, 64); t.y += __shfl(t.y, lane+30, 64);
  t.z += __shfl(t.z, lane+30, 64); t.w += __shfl(t.w, lane+30, 64);
  t.x += __shfl(t.x, lane+15, 64); t.y += __shfl(t.y, lane+15, 64);
  t.z += __shfl(t.z, lane+15, 64); t.w += __shfl(t.w, lane+15, 64);
  float ux = __shfl(t.x, lane+5, 64),  uy = __shfl(t.y, lane+5, 64);
  float uz = __shfl(t.z, lane+5, 64),  uw = __shfl(t.w, lane+5, 64);
  float wx = __shfl(t.x, lane+10, 64), wy = __shfl(t.y, lane+10, 64);
  float wz = __shfl(t.z, lane+10, 64), ww = __shfl(t.w, lane+10, 64);
  if(lane < 5){
    float tx = t.x + ux + wx, ty = t.y + uy + wy;
    float tz = t.z + uz + wz, tw = t.w + uw + ww;
    int d = r1 - r0;
    float bx, by, bz, bw;
    if(d > 0){
      float inv = 1.f/(float)d;
      bx = tx*inv; by = ty*inv; bz = tz*inv; bw = tw*inv;
    } else {
      uint2 v = *(const uint2*)&y2b[(size_t)wid*DGD + lane*4];
      bx = __uint_as_float(v.x << 16);
      by = __uint_as_float(v.x & 0xffff0000u);
      bz = __uint_as_float(v.y << 16);
      bw = __uint_as_float(v.y & 0xffff0000u);
    }
    float4 o;
    o.x = fmaxf(bx + b2[lane*4+0], 0.f);
    o.y = fmaxf(by + b2[lane*4+1], 0.f);
    o.z = fmaxf(bz + b2[lane*4+2], 0.f);
    o.w = fmaxf(bw + b2[lane*4+3], 0.f);
    *(float4*)&y3[(size_t)wid*DGD + lane*4] = o;
  }
}

// head3: per-graph mean + attention softmax + DIRECT A' row write (bf16)
__global__ __launch_bounds__(256) void k_head3(const float* __restrict__ y3,
      const int* __restrict__ gofs, const float* __restrict__ Wat,
      const float* __restrict__ desc2d, ushort* __restrict__ Ab){
  int g = blockIdx.x, t = threadIdx.x;
  int n0 = gofs[g], n1 = gofs[g+1];
  int cnt = n1 - n0;
  __shared__ float part[240];
  __shared__ float hgaL[21];
  __shared__ float daaL[201];
  __shared__ float red[256];
  if(t < 240){
    int grp = t/20, dim = t - grp*20;
    float a = 0.f;
    for(int n = n0 + grp; n < n1; n += 12) a += y3[(size_t)n*DGD + dim];
    part[t] = a;
  }
  __syncthreads();
  if(t < DGD){
    float s = 0.f;
    #pragma unroll
    for(int k=0;k<12;k++) s += part[k*20 + t];
    hgaL[t] = s / (float)max(cnt, 1);
  }
  if(t == DGD) hgaL[20] = 1.f;
  __syncthreads();
  float logit = 0.f;
  if(t < DD2){
    #pragma unroll
    for(int k=0;k<DGD;k++) logit += hgaL[k]*Wat[k*DD2 + t];
  }
  float v = (t < DD2) ? logit : -1e30f;
  red[t] = v; __syncthreads();
  for(int off=128; off>=1; off>>=1){ if(t<off) red[t]=fmaxf(red[t],red[t+off]); __syncthreads(); }
  float mx = red[0]; __syncthreads();
  float e = (t < DD2) ? expf(logit - mx) : 0.f;
  red[t] = e; __syncthreads();
  for(int off=128; off>=1; off>>=1){ if(t<off) red[t]+=red[t+off]; __syncthreads(); }
  float s = red[0];
  if(t < DD2) daaL[t] = (e/s)*desc2d[(size_t)g*DD2 + t];
  if(t == DD2) daaL[200] = 1.f;
  __syncthreads();
  ushort* arow = Ab + (size_t)g*KPAD;
  #pragma unroll
  for(int p=0;p<17;p++){
    int k = t + 256*p;
    ushort o = 0;
    if(k < 4221){
      int i = (int)(((uint)k * 83470u) >> 24);   // floor(k/201), exact for k<4221
      int j = k - i*201;
      o = f2bf(hgaL[i]*daaL[j]);
    }
    arow[k] = o;
  }
}

// ---------------- fusion GEMM v6: single-B bf16, M-tile 64, grid (64,8) -----
__global__ __launch_bounds__(256) void k_fuse6(const ushort* __restrict__ Ab,
                                               const ushort* __restrict__ Bthi,
                                               float* __restrict__ zp){
  __shared__ ushort Al[64][40];
  __shared__ ushort Bl[128][40];
  int tid = threadIdx.x;
  int m0 = blockIdx.x * 64;
  int seg = blockIdx.y;
  int lane = tid & 63;
  int w = tid >> 6;
  int wm = (w >> 1) * 32;
  int wn = (w & 1) * 64;
  f32x4 acc[2][4];
  #pragma unroll
  for(int a=0;a<2;a++)
    #pragma unroll
    for(int b=0;b<4;b++) acc[a][b] = (f32x4){0.f,0.f,0.f,0.f};

  int ar = tid >> 2;
  int as = (tid & 3) * 8;
  int br = tid >> 1;
  int bs = (tid & 1) * 16;
  const uint4* gA = (const uint4*)(Ab   + (size_t)(m0 + ar)*KPAD + seg*KSEG + as);
  const uint4* gB = (const uint4*)(Bthi + (size_t)br*KPAD + seg*KSEG + bs);

  int frow = lane & 15;
  int fk   = (lane >> 4) * 8;

  for(int ks=0; ks<17; ks++){
    uint4 va = gA[0];
    uint4 vb0 = gB[0], vb1 = gB[1];
    gA += 4; gB += 4;                // one k-step = 32 shorts = 4 uint4
    __syncthreads();
    *(uint4*)&Al[ar][as]   = va;
    *(uint4*)&Bl[br][bs]   = vb0;
    *(uint4*)&Bl[br][bs+8] = vb1;
    __syncthreads();
    bf16x8 af[2], bh[4];
    #pragma unroll
    for(int mt=0;mt<2;mt++) af[mt] = *(const bf16x8*)&Al[wm + mt*16 + frow][fk];
    #pragma unroll
    for(int nt=0;nt<4;nt++) bh[nt] = *(const bf16x8*)&Bl[wn + nt*16 + frow][fk];
    #pragma unroll
    for(int mt=0;mt<2;mt++)
      #pragma unroll
      for(int nt=0;nt<4;nt++)
        acc[mt][nt] = __builtin_amdgcn_mfma_f32_16x16x32_bf16(af[mt], bh[nt], acc[mt][nt], 0, 0, 0);
  }
  float* zb = zp + ((size_t)seg*NB + m0)*128;
  int drow = (lane >> 4) * 4;
  int dcol = lane & 15;
  #pragma unroll
  for(int mt=0;mt<2;mt++)
    #pragma unroll
    for(int nt=0;nt<4;nt++)
      #pragma unroll
      for(int rr=0;rr<4;rr++)
        zb[(size_t)(wm + mt*16 + drow + rr)*128 + wn + nt*16 + dcol] = acc[mt][nt][rr];
}

__global__ void k_reduce(const float* __restrict__ zp, const float* __restrict__ b1,
                         float* __restrict__ z1){
  int idx = blockIdx.x*256 + threadIdx.x;
  if(idx >= NB*32) return;
  const float4* z = (const float4*)zp;
  float4 o = ((const float4*)b1)[idx & 31];
  #pragma unroll
  for(int s=0;s<NSEG;s++){
    float4 a = z[idx + (size_t)s*NB*32];
    o.x += a.x; o.y += a.y; o.z += a.z; o.w += a.w;
  }
  ((float4*)z1)[idx] = o;
}

// BN stats -> folded scale/shift
__global__ void k_bnstats(const float* __restrict__ X, int C,
                          const float* __restrict__ gamma, const float* __restrict__ beta,
                          float* __restrict__ scale, float* __restrict__ shift){
  int c = blockIdx.x;
  float s=0.f, s2=0.f;
  for(int r=threadIdx.x; r<NB; r+=256){
    float v = X[(size_t)r*C + c];
    s += v; s2 += v*v;
  }
  __shared__ float sh[256], sh2[256];
  sh[threadIdx.x]=s; sh2[threadIdx.x]=s2;
  __syncthreads();
  for(int off=128; off>=1; off>>=1){
    if(threadIdx.x<off){ sh[threadIdx.x]+=sh[threadIdx.x+off]; sh2[threadIdx.x]+=sh2[threadIdx.x+off]; }
    __syncthreads();
  }
  if(threadIdx.x==0){
    float mu  = sh[0]*(1.0f/NB);
    float var = sh2[0]*(1.0f/NB) - mu*mu;
    float a = gamma[c]*rsqrtf(var + 1e-5f);
    scale[c] = a;
    shift[c] = beta[c] - mu*a;
  }
}

__global__ void k_mlp2(const float* __restrict__ z1, const float* __restrict__ sc,
                       const float* __restrict__ sf, const float* __restrict__ W,
                       const float* __restrict__ bias, float* __restrict__ out){
  __shared__ float Wl[DM1*DM2];
  __shared__ float scl[DM1], sfl[DM1];
  for(int idx=threadIdx.x; idx<DM1*DM2; idx+=256) Wl[idx] = W[idx];
  if(threadIdx.x < DM1){ scl[threadIdx.x]=sc[threadIdx.x]; sfl[threadIdx.x]=sf[threadIdx.x]; }
  __syncthreads();
  int idx = blockIdx.x*256 + threadIdx.x;
  int r = idx >> 5, o = idx & 31;
  if(r >= NB) return;
  float acc = bias[o];
  const float* xr = z1 + (size_t)r*DM1;
  for(int k=0;k<DM1;k++){
    float xn = fmaxf(xr[k]*scl[k] + sfl[k], 0.f);
    acc += xn * Wl[k*DM2 + o];
  }
  out[(size_t)r*DM2 + o] = acc;
}

__global__ void k_final(const float* __restrict__ z2, const float* __restrict__ sc2,
                        const float* __restrict__ sf2, const float* __restrict__ W3,
                        const float* __restrict__ b3, float* __restrict__ out){
  int r = blockIdx.x*256 + threadIdx.x;
  if(r >= NB) return;
  float acc = b3[0];
  const float* xr = z2 + (size_t)r*DM2;
  #pragma unroll
  for(int o=0;o<DM2;o++){
    float xn = fmaxf(xr[o]*sc2[o] + sf2[o], 0.f);
    acc += xn * W3[o];
  }
  out[r] = acc;
}

extern "C" void kernel_launch(void* const* d_in, const int* in_sizes, int n_in,
                              void* d_out, int out_size, void* d_ws, size_t ws_size,
                              hipStream_t stream){
  (void)in_sizes; (void)n_in; (void)out_size; (void)ws_size;
  const float* feat   = (const float*)d_in[0];
  const float* desc2d = (const float*)d_in[1];
  const int*   esrc   = (const int*)d_in[3];
  const int*   edst   = (const int*)d_in[4];
  const int*   gid    = (const int*)d_in[5];
  const float* Wg1    = (const float*)d_in[6];
  const float* bg1    = (const float*)d_in[7];
  const float* Wg2    = (const float*)d_in[8];
  const float* bg2    = (const float*)d_in[9];
  const float* Wat    = (const float*)d_in[10];
  const float* Wf1    = (const float*)d_in[11];
  const float* bf1    = (const float*)d_in[12];
  const float* Wf2    = (const float*)d_in[13];
  const float* bf2    = (const float*)d_in[14];
  const float* Wf3    = (const float*)d_in[15];
  const float* bf3    = (const float*)d_in[16];
  const float* gamma1 = (const float*)d_in[17];
  const float* beta1  = (const float*)d_in[18];
  const float* gamma2 = (const float*)d_in[19];
  const float* beta2  = (const float*)d_in[20];
  float* out = (float*)d_out;

  char* base = (char*)d_ws;
  size_t off = 0;
  auto alloc = [&](size_t bytes)->void*{
    void* r = base + off;
    off = (off + bytes + 255) & ~(size_t)255;
    return r;
  };
  int*    rowptr = (int*)   alloc((size_t)(NN+1)*4);
  int*    gofs   = (int*)   alloc((size_t)(NB+1)*4);
  int*    adj    = (int*)   alloc((size_t)NE*4);
  int*    bukCur = (int*)   alloc((size_t)NBUK*4);
  float*  sc1    = (float*) alloc((size_t)DM1*4);
  float*  sf1    = (float*) alloc((size_t)DM1*4);
  float*  sc2    = (float*) alloc((size_t)DM2*4);
  float*  sf2    = (float*) alloc((size_t)DM2*4);
  ushort* W1thi  = (ushort*)alloc((size_t)128*KPAD*2);
  ushort* W1tb   = (ushort*)alloc((size_t)112*96*2);
  ushort* W2tb   = (ushort*)alloc((size_t)32*128*2);
  float*  z1     = (float*) alloc((size_t)NB*DM1*4);
  float*  z2     = (float*) alloc((size_t)NB*DM2*4);
  // R1 (32 MB): pairs(14.3M) -> agg80b(16M) -> zp(16.8M); y3 at +17M (8M)
  char*   R1     = (char*)  alloc((size_t)NN*DPAD*4);
  // R2 (35.7 MB): featb(16M) + y2b(@16M, 4M) -> Ab(35.7M)
  char*   R2     = (char*)  alloc((size_t)NB*KPAD*2);
  uint2*  pairs  = (uint2*) R1;
  ushort* agg80b = (ushort*)R1;
  float*  zp     = (float*) R1;
  float*  y3     = (float*) (R1 + (size_t)17*1024*1024);
  ushort* featb  = (ushort*)R2;
  ushort* y2b    = (ushort*)(R2 + (size_t)NN*DPAD*2);
  ushort* Ab     = (ushort*)R2;

  hipMemsetAsync(bukCur, 0, (size_t)NBUK*4, stream);

  k_pre <<<PRE_BUK + PRE_PREP, 256, 0, stream>>>(
      esrc, edst, bukCur, pairs, Wf1, W1thi, Wg1, W1tb, Wg2, W2tb);
  k_cvt <<<(NN*DPAD+255)/256, 256, 0, stream>>>(feat, featb);
  k_csr2<<<NBUK + GOFS_BLKS, 512, 0, stream>>>(pairs, bukCur, rowptr, adj, gid, gofs);

  k_agg1e <<<(NN+3)/4, 256, 0, stream>>>(featb, feat, rowptr, adj, agg80b);
  k_gcn12 <<<(NN+127)/128, 256, 0, stream>>>(agg80b, W1tb, W2tb, bg1, y2b);
  k_agg2d <<<(NN+3)/4, 256, 0, stream>>>(y2b, rowptr, adj, bg2, y3);

  k_head3<<<NB, 256, 0, stream>>>(y3, gofs, Wat, desc2d, Ab);
  k_fuse6<<<dim3(64, NSEG), 256, 0, stream>>>(Ab, W1thi, zp);
  k_reduce<<<(NB*32+255)/256, 256, 0, stream>>>(zp, bf1, z1);

  k_bnstats<<<DM1, 256, 0, stream>>>(z1, DM1, gamma1, beta1, sc1, sf1);
  k_mlp2   <<<(NB*DM2)/256, 256, 0, stream>>>(z1, sc1, sf1, Wf2, bf2, z2);
  k_bnstats<<<DM2, 256, 0, stream>>>(z2, DM2, gamma2, beta2, sc2, sf2);
  k_final  <<<(NB+255)/256, 256, 0, stream>>>(z2, sc2, sf2, Wf3, bf3, out);
}